// Round 1
// baseline (2453.645 us; speedup 1.0000x reference)
//
#include <hip/hip_runtime.h>

#define NN 50000      // nodes
#define EE 500000     // raw edges
#define ET 550000     // edges + self loops
#define EMB 128
#define HID 256
#define NH 8
#define RP 64

__device__ __forceinline__ float lrelu(float v) { return v > 0.f ? v : 0.2f * v; }

// h1 = x @ W1  [N,256]; a_src/a_dst[n,h] = sum_d h1[n,h,d]*att[h,d]
// 256 thr/block, 8 nodes/block, grid = N/8
__global__ __launch_bounds__(256) void k_gemm1(const float* __restrict__ x,
    const float* __restrict__ W1, const float* __restrict__ asw,
    const float* __restrict__ adw, float* __restrict__ h1,
    float* __restrict__ a_src, float* __restrict__ a_dst) {
  __shared__ float xs[8][EMB];
  const int tid = threadIdx.x;
  const int node0 = blockIdx.x << 3;
  for (int i = tid; i < 8 * EMB; i += 256)
    xs[i >> 7][i & 127] = x[(size_t)node0 * EMB + i];
  __syncthreads();
  const int c = tid;
  float acc[8] = {0, 0, 0, 0, 0, 0, 0, 0};
  for (int k = 0; k < EMB; k++) {
    float w = W1[k * HID + c];
#pragma unroll
    for (int r = 0; r < 8; r++) acc[r] += xs[r][k] * w;
  }
  const float as = asw[c], ad = adw[c];
  const int lane = tid & 63;
#pragma unroll
  for (int r = 0; r < 8; r++) {
    int n = node0 + r;
    h1[(size_t)n * HID + c] = acc[r];
    float vs = acc[r] * as, vd = acc[r] * ad;
#pragma unroll
    for (int d = 16; d; d >>= 1) {
      vs += __shfl_down(vs, d, 32);
      vd += __shfl_down(vd, d, 32);
    }
    if ((lane & 31) == 0) {
      a_src[n * NH + (c >> 5)] = vs;
      a_dst[n * NH + (c >> 5)] = vd;
    }
  }
}

// softmax denominators layer 1: s1[dst,h] += exp(lrelu(a_src[src,h]+a_dst[dst,h]))
__global__ __launch_bounds__(256) void k_esum1(const int* __restrict__ es,
    const int* __restrict__ ed, const float* __restrict__ a_src,
    const float* __restrict__ a_dst, float* __restrict__ s1) {
  int i = blockIdx.x * 256 + threadIdx.x;
  if (i >= ET) return;
  int s, d;
  if (i < EE) { s = es[i]; d = ed[i]; } else { s = d = i - EE; }
  float4 s0 = *(const float4*)(a_src + (size_t)s * NH);
  float4 s1v = *(const float4*)(a_src + (size_t)s * NH + 4);
  float4 d0 = *(const float4*)(a_dst + (size_t)d * NH);
  float4 d1 = *(const float4*)(a_dst + (size_t)d * NH + 4);
  float e[8] = {s0.x + d0.x, s0.y + d0.y, s0.z + d0.z, s0.w + d0.w,
                s1v.x + d1.x, s1v.y + d1.y, s1v.z + d1.z, s1v.w + d1.w};
  float* base = s1 + (size_t)d * NH;
#pragma unroll
  for (int h = 0; h < NH; h++) atomicAdd(base + h, __expf(lrelu(e[h])));
}

// message pass layer 1: one wave per edge; lane handles 4 cols (float4)
__global__ __launch_bounds__(256) void k_emsg1(const int* __restrict__ es,
    const int* __restrict__ ed, const float* __restrict__ a_src,
    const float* __restrict__ a_dst, const float* __restrict__ s1,
    const float* __restrict__ h1, float* __restrict__ out1) {
  int w = (blockIdx.x * 256 + threadIdx.x) >> 6;
  int lane = threadIdx.x & 63;
  if (w >= ET) return;
  int s, d;
  if (w < EE) { s = es[w]; d = ed[w]; } else { s = d = w - EE; }
  float alpha = 0.f;
  if (lane < NH) {
    float v = lrelu(a_src[(size_t)s * NH + lane] + a_dst[(size_t)d * NH + lane]);
    alpha = __expf(v) / (s1[(size_t)d * NH + lane] + 1e-16f);
  }
  alpha = __shfl(alpha, lane >> 3);  // head = (4*lane)/32 = lane>>3
  float4 hv = ((const float4*)(h1 + (size_t)s * HID))[lane];
  float* po = out1 + (size_t)d * HID + (lane << 2);
  atomicAdd(po + 0, hv.x * alpha);
  atomicAdd(po + 1, hv.y * alpha);
  atomicAdd(po + 2, hv.z * alpha);
  atomicAdd(po + 3, hv.w * alpha);
}

// x2 = elu(out1 + b1), in place
__global__ __launch_bounds__(256) void k_elu(float* __restrict__ x,
                                             const float* __restrict__ b1) {
  size_t i = (size_t)blockIdx.x * 256 + threadIdx.x;
  float v = x[i] + b1[i & 255];
  x[i] = v > 0.f ? v : __expf(v) - 1.f;
}

// h2 = x2 @ W2 [N,64]; a2 scalars. 256 thr/block (4 waves), 16 nodes/block.
__global__ __launch_bounds__(256) void k_gemm2(const float* __restrict__ x2,
    const float* __restrict__ W2, const float* __restrict__ asw,
    const float* __restrict__ adw, float* __restrict__ h2,
    float* __restrict__ a_src2, float* __restrict__ a_dst2) {
  __shared__ float xs[16 * HID];
  const int tid = threadIdx.x;
  const int node0 = blockIdx.x << 4;
  for (int i = tid; i < 16 * HID; i += 256) xs[i] = x2[(size_t)node0 * HID + i];
  __syncthreads();
  const int lane = tid & 63, q = tid >> 6;
  float acc[4] = {0, 0, 0, 0};
  for (int k = 0; k < HID; k++) {
    float wv = W2[k * RP + lane];
#pragma unroll
    for (int j = 0; j < 4; j++) acc[j] += xs[(q * 4 + j) * HID + k] * wv;
  }
  const float as = asw[lane], ad = adw[lane];
#pragma unroll
  for (int j = 0; j < 4; j++) {
    int n = node0 + q * 4 + j;
    h2[(size_t)n * RP + lane] = acc[j];
    float vs = acc[j] * as, vd = acc[j] * ad;
#pragma unroll
    for (int dd = 32; dd; dd >>= 1) {
      vs += __shfl_down(vs, dd, 64);
      vd += __shfl_down(vd, dd, 64);
    }
    if (lane == 0) { a_src2[n] = vs; a_dst2[n] = vd; }
  }
}

__global__ __launch_bounds__(256) void k_initout(float* __restrict__ o,
                                                 const float* __restrict__ b2) {
  size_t i = (size_t)blockIdx.x * 256 + threadIdx.x;
  o[i] = b2[i & 63];
}

__global__ __launch_bounds__(256) void k_esum2(const int* __restrict__ es,
    const int* __restrict__ ed, const float* __restrict__ a_src2,
    const float* __restrict__ a_dst2, float* __restrict__ s2) {
  int i = blockIdx.x * 256 + threadIdx.x;
  if (i >= ET) return;
  int s, d;
  if (i < EE) { s = es[i]; d = ed[i]; } else { s = d = i - EE; }
  atomicAdd(&s2[d], __expf(lrelu(a_src2[s] + a_dst2[d])));
}

// message pass layer 2: one wave per edge, one lane per col (64 cols)
__global__ __launch_bounds__(256) void k_emsg2(const int* __restrict__ es,
    const int* __restrict__ ed, const float* __restrict__ a_src2,
    const float* __restrict__ a_dst2, const float* __restrict__ s2,
    const float* __restrict__ h2, float* __restrict__ out) {
  int w = (blockIdx.x * 256 + threadIdx.x) >> 6;
  int lane = threadIdx.x & 63;
  if (w >= ET) return;
  int s, d;
  if (w < EE) { s = es[w]; d = ed[w]; } else { s = d = w - EE; }
  float alpha = 0.f;
  if (lane == 0)
    alpha = __expf(lrelu(a_src2[s] + a_dst2[d])) / (s2[d] + 1e-16f);
  alpha = __shfl(alpha, 0);
  atomicAdd(out + (size_t)d * RP + lane, h2[(size_t)s * RP + lane] * alpha);
}

extern "C" void kernel_launch(void* const* d_in, const int* in_sizes, int n_in,
                              void* d_out, int out_size, void* d_ws, size_t ws_size,
                              hipStream_t stream) {
  const float* x   = (const float*)d_in[0];
  const float* W1  = (const float*)d_in[1];
  const float* a1s = (const float*)d_in[2];
  const float* a1d = (const float*)d_in[3];
  const float* b1  = (const float*)d_in[4];
  const float* W2  = (const float*)d_in[5];
  const float* a2s = (const float*)d_in[6];
  const float* a2d = (const float*)d_in[7];
  const float* b2  = (const float*)d_in[8];
  const int*   es  = (const int*)d_in[9];
  const int*   ed  = es + EE;
  float* out = (float*)d_out;

  float* ws    = (float*)d_ws;
  float* h1    = ws;                          // N*256
  float* out1  = h1 + (size_t)NN * HID;       // N*256 (becomes x2 after ELU)
  float* asrc1 = out1 + (size_t)NN * HID;     // N*8
  float* adst1 = asrc1 + (size_t)NN * NH;     // N*8
  float* s1    = adst1 + (size_t)NN * NH;     // N*8
  // layer-2 buffers reuse layer-1 storage (dead after k_emsg1)
  float* h2    = h1;      // N*64 <= N*256
  float* asrc2 = asrc1;   // N
  float* adst2 = adst1;   // N
  float* s2    = s1;      // N

  hipMemsetAsync(s1, 0, (size_t)NN * NH * sizeof(float), stream);
  hipMemsetAsync(out1, 0, (size_t)NN * HID * sizeof(float), stream);

  k_gemm1<<<NN / 8, 256, 0, stream>>>(x, W1, a1s, a1d, h1, asrc1, adst1);
  k_esum1<<<(ET + 255) / 256, 256, 0, stream>>>(es, ed, asrc1, adst1, s1);
  k_emsg1<<<(ET * 64 + 255) / 256, 256, 0, stream>>>(es, ed, asrc1, adst1, s1, h1, out1);
  k_elu<<<NN * HID / 256, 256, 0, stream>>>(out1, b1);
  k_gemm2<<<NN / 16, 256, 0, stream>>>(out1, W2, a2s, a2d, h2, asrc2, adst2);

  hipMemsetAsync(s2, 0, (size_t)NN * sizeof(float), stream);
  k_initout<<<(NN * RP) / 256, 256, 0, stream>>>(out, b2);
  k_esum2<<<(ET + 255) / 256, 256, 0, stream>>>(es, ed, asrc2, adst2, s2);
  k_emsg2<<<(ET * 64 + 255) / 256, 256, 0, stream>>>(es, ed, asrc2, adst2, s2, h2, out);
}

// Round 2
// 546.833 us; speedup vs baseline: 4.4870x; 4.4870x over previous
//
#include <hip/hip_runtime.h>

#define NN 50000      // nodes
#define EE 500000     // raw edges
#define ET 550000     // edges + self loops
#define EMB 128
#define HID 256
#define NH 8
#define RP 64
#define SCAN_T 256
#define SCAN_C 196    // ceil(50000/256)

__device__ __forceinline__ float lrelu(float v) { return v > 0.f ? v : 0.2f * v; }
__device__ __forceinline__ float elu(float v) { return v > 0.f ? v : __expf(v) - 1.f; }

// ---------------- GEMM 1: h1 = x @ W1 [N,256]; per-head att dots ----------
__global__ __launch_bounds__(256) void k_gemm1(const float* __restrict__ x,
    const float* __restrict__ W1, const float* __restrict__ asw,
    const float* __restrict__ adw, float* __restrict__ h1,
    float* __restrict__ a_src, float* __restrict__ a_dst) {
  __shared__ float xs[8][EMB];
  const int tid = threadIdx.x;
  const int node0 = blockIdx.x << 3;
  for (int i = tid; i < 8 * EMB; i += 256)
    xs[i >> 7][i & 127] = x[(size_t)node0 * EMB + i];
  __syncthreads();
  const int c = tid;
  float acc[8] = {0, 0, 0, 0, 0, 0, 0, 0};
  for (int k = 0; k < EMB; k++) {
    float w = W1[k * HID + c];
#pragma unroll
    for (int r = 0; r < 8; r++) acc[r] += xs[r][k] * w;
  }
  const float as = asw[c], ad = adw[c];
  const int lane = tid & 63;
#pragma unroll
  for (int r = 0; r < 8; r++) {
    int n = node0 + r;
    h1[(size_t)n * HID + c] = acc[r];
    float vs = acc[r] * as, vd = acc[r] * ad;
#pragma unroll
    for (int d = 16; d; d >>= 1) {
      vs += __shfl_down(vs, d, 32);
      vd += __shfl_down(vd, d, 32);
    }
    if ((lane & 31) == 0) {
      a_src[n * NH + (c >> 5)] = vs;
      a_dst[n * NH + (c >> 5)] = vd;
    }
  }
}

// ---------------- CSR build (by dst) --------------------------------------
__global__ __launch_bounds__(256) void k_deg(const int* __restrict__ ed,
                                             int* __restrict__ deg) {
  int i = blockIdx.x * 256 + threadIdx.x;
  if (i >= ET) return;
  int d = (i < EE) ? ed[i] : i - EE;
  atomicAdd(&deg[d], 1);
}

// single-block scan: rowp = exclusive_scan(deg); cursor = rowp (working copy)
__global__ __launch_bounds__(SCAN_T) void k_scan(const int* __restrict__ deg,
    int* __restrict__ rowp, int* __restrict__ cursor) {
  __shared__ int sums[SCAN_T];
  const int t = threadIdx.x;
  const int base = t * SCAN_C;
  int s = 0;
  for (int j = 0; j < SCAN_C; j++) {
    int idx = base + j;
    if (idx < NN) s += deg[idx];
  }
  sums[t] = s;
  __syncthreads();
  for (int off = 1; off < SCAN_T; off <<= 1) {
    int v = (t >= off) ? sums[t - off] : 0;
    __syncthreads();
    sums[t] += v;
    __syncthreads();
  }
  int run = (t == 0) ? 0 : sums[t - 1];
  for (int j = 0; j < SCAN_C; j++) {
    int idx = base + j;
    if (idx < NN) {
      rowp[idx] = run;
      cursor[idx] = run;
      run += deg[idx];
    }
  }
  if (t == SCAN_T - 1) rowp[NN] = run;
}

__global__ __launch_bounds__(256) void k_fill(const int* __restrict__ es,
    const int* __restrict__ ed, int* __restrict__ cursor, int* __restrict__ col) {
  int i = blockIdx.x * 256 + threadIdx.x;
  if (i >= ET) return;
  int s, d;
  if (i < EE) { s = es[i]; d = ed[i]; } else { s = d = i - EE; }
  int pos = atomicAdd(&cursor[d], 1);
  col[pos] = s;
}

// ---------------- Layer-1 aggregation (fused softmax+gather+bias+ELU) -----
// one wave per dst node; lane owns 4 cols (float4), head = lane>>3
__global__ __launch_bounds__(256) void k_agg1(const int* __restrict__ rowp,
    const int* __restrict__ col, const float* __restrict__ a_src,
    const float* __restrict__ a_dst, const float* __restrict__ h1,
    const float* __restrict__ b1, float* __restrict__ x2) {
  int node = (blockIdx.x * 256 + threadIdx.x) >> 6;
  int lane = threadIdx.x & 63;
  if (node >= NN) return;
  const int h = lane >> 3;
  const float ad = a_dst[node * NH + h];
  float4 num = {0.f, 0.f, 0.f, 0.f};
  float den = 0.f;  // replicated across the 8 lanes of each head
  const int beg = rowp[node], end = rowp[node + 1];
  for (int e = beg; e < end; e++) {
    int s = col[e];
    float w = __expf(lrelu(a_src[s * NH + h] + ad));
    den += w;
    float4 hv = ((const float4*)(h1 + (size_t)s * HID))[lane];
    num.x += w * hv.x;
    num.y += w * hv.y;
    num.z += w * hv.z;
    num.w += w * hv.w;
  }
  const float inv = 1.f / (den + 1e-16f);
  float4 b = ((const float4*)b1)[lane];
  float4 o;
  o.x = elu(num.x * inv + b.x);
  o.y = elu(num.y * inv + b.y);
  o.z = elu(num.z * inv + b.z);
  o.w = elu(num.w * inv + b.w);
  ((float4*)(x2 + (size_t)node * HID))[lane] = o;
}

// ---------------- GEMM 2: h2 = x2 @ W2 [N,64]; scalar att dots ------------
__global__ __launch_bounds__(256) void k_gemm2(const float* __restrict__ x2,
    const float* __restrict__ W2, const float* __restrict__ asw,
    const float* __restrict__ adw, float* __restrict__ h2,
    float* __restrict__ a_src2, float* __restrict__ a_dst2) {
  __shared__ float xs[16 * HID];
  const int tid = threadIdx.x;
  const int node0 = blockIdx.x << 4;
  for (int i = tid; i < 16 * HID; i += 256) xs[i] = x2[(size_t)node0 * HID + i];
  __syncthreads();
  const int lane = tid & 63, q = tid >> 6;
  float acc[4] = {0, 0, 0, 0};
  for (int k = 0; k < HID; k++) {
    float wv = W2[k * RP + lane];
#pragma unroll
    for (int j = 0; j < 4; j++) acc[j] += xs[(q * 4 + j) * HID + k] * wv;
  }
  const float as = asw[lane], ad = adw[lane];
#pragma unroll
  for (int j = 0; j < 4; j++) {
    int n = node0 + q * 4 + j;
    h2[(size_t)n * RP + lane] = acc[j];
    float vs = acc[j] * as, vd = acc[j] * ad;
#pragma unroll
    for (int dd = 32; dd; dd >>= 1) {
      vs += __shfl_down(vs, dd, 64);
      vd += __shfl_down(vd, dd, 64);
    }
    if (lane == 0) { a_src2[n] = vs; a_dst2[n] = vd; }
  }
}

// ---------------- Layer-2 aggregation (fused softmax+gather+bias) ---------
// one wave per dst node; lane owns 1 of 64 cols
__global__ __launch_bounds__(256) void k_agg2(const int* __restrict__ rowp,
    const int* __restrict__ col, const float* __restrict__ a_src2,
    const float* __restrict__ a_dst2, const float* __restrict__ h2,
    const float* __restrict__ b2, float* __restrict__ out) {
  int node = (blockIdx.x * 256 + threadIdx.x) >> 6;
  int lane = threadIdx.x & 63;
  if (node >= NN) return;
  const float ad = a_dst2[node];
  float num = 0.f, den = 0.f;
  const int beg = rowp[node], end = rowp[node + 1];
  for (int e = beg; e < end; e++) {
    int s = col[e];
    float w = __expf(lrelu(a_src2[s] + ad));
    den += w;
    num += w * h2[(size_t)s * RP + lane];
  }
  out[(size_t)node * RP + lane] = num / (den + 1e-16f) + b2[lane];
}

extern "C" void kernel_launch(void* const* d_in, const int* in_sizes, int n_in,
                              void* d_out, int out_size, void* d_ws, size_t ws_size,
                              hipStream_t stream) {
  const float* x   = (const float*)d_in[0];
  const float* W1  = (const float*)d_in[1];
  const float* a1s = (const float*)d_in[2];
  const float* a1d = (const float*)d_in[3];
  const float* b1  = (const float*)d_in[4];
  const float* W2  = (const float*)d_in[5];
  const float* a2s = (const float*)d_in[6];
  const float* a2d = (const float*)d_in[7];
  const float* b2  = (const float*)d_in[8];
  const int*   es  = (const int*)d_in[9];
  const int*   ed  = es + EE;
  float* out = (float*)d_out;

  // workspace layout (floats then ints)
  float* ws    = (float*)d_ws;
  float* h1    = ws;                          // N*256 (later reused as h2: N*64)
  float* x2    = h1 + (size_t)NN * HID;       // N*256
  float* asrc1 = x2 + (size_t)NN * HID;       // N*8
  float* adst1 = asrc1 + (size_t)NN * NH;     // N*8
  int*   deg   = (int*)(adst1 + (size_t)NN * NH);  // N
  int*   rowp  = deg + NN;                    // N+1
  int*   cursor = rowp + NN + 1;              // N
  int*   col   = cursor + NN;                 // ET
  // layer-2 reuses layer-1 storage
  float* h2    = h1;      // N*64
  float* asrc2 = asrc1;   // N
  float* adst2 = adst1;   // N

  hipMemsetAsync(deg, 0, (size_t)NN * sizeof(int), stream);

  // CSR build (independent of gemm1; cheap)
  k_deg<<<(ET + 255) / 256, 256, 0, stream>>>(ed, deg);
  k_scan<<<1, SCAN_T, 0, stream>>>(deg, rowp, cursor);
  k_fill<<<(ET + 255) / 256, 256, 0, stream>>>(es, ed, cursor, col);

  // layer 1
  k_gemm1<<<NN / 8, 256, 0, stream>>>(x, W1, a1s, a1d, h1, asrc1, adst1);
  k_agg1<<<(NN * 64 + 255) / 256, 256, 0, stream>>>(rowp, col, asrc1, adst1, h1, b1, x2);

  // layer 2
  k_gemm2<<<NN / 16, 256, 0, stream>>>(x2, W2, a2s, a2d, h2, asrc2, adst2);
  k_agg2<<<(NN * 64 + 255) / 256, 256, 0, stream>>>(rowp, col, asrc2, adst2, h2, b2, out);
}

// Round 3
// 417.657 us; speedup vs baseline: 5.8748x; 1.3093x over previous
//
#include <hip/hip_runtime.h>

#define NN 50000      // nodes
#define EE 500000     // raw edges
#define ET 550000     // edges + self loops
#define EMB 128
#define HID 256
#define NH 8
#define RP 64
#define NBLK ((NN + 255) / 256)   // 196 scan blocks

__device__ __forceinline__ float lrelu(float v) { return v > 0.f ? v : 0.2f * v; }
__device__ __forceinline__ float elu(float v) { return v > 0.f ? v : __expf(v) - 1.f; }

// ---------------- GEMM 1: h1 = x @ W1 [N,256]; per-head att dots ----------
__global__ __launch_bounds__(256) void k_gemm1(const float* __restrict__ x,
    const float* __restrict__ W1, const float* __restrict__ asw,
    const float* __restrict__ adw, float* __restrict__ h1,
    float* __restrict__ a_src, float* __restrict__ a_dst) {
  __shared__ float xs[8][EMB];
  const int tid = threadIdx.x;
  const int node0 = blockIdx.x << 3;
  for (int i = tid; i < 8 * EMB; i += 256)
    xs[i >> 7][i & 127] = x[(size_t)node0 * EMB + i];
  __syncthreads();
  const int c = tid;
  float acc[8] = {0, 0, 0, 0, 0, 0, 0, 0};
  for (int k = 0; k < EMB; k++) {
    float w = W1[k * HID + c];
#pragma unroll
    for (int r = 0; r < 8; r++) acc[r] += xs[r][k] * w;
  }
  const float as = asw[c], ad = adw[c];
  const int lane = tid & 63;
#pragma unroll
  for (int r = 0; r < 8; r++) {
    int n = node0 + r;
    h1[(size_t)n * HID + c] = acc[r];
    float vs = acc[r] * as, vd = acc[r] * ad;
#pragma unroll
    for (int d = 16; d; d >>= 1) {
      vs += __shfl_down(vs, d, 32);
      vd += __shfl_down(vd, d, 32);
    }
    if ((lane & 31) == 0) {
      a_src[n * NH + (c >> 5)] = vs;
      a_dst[n * NH + (c >> 5)] = vd;
    }
  }
}

// ---------------- CSR build (by dst) --------------------------------------
__global__ __launch_bounds__(256) void k_deg(const int* __restrict__ ed,
                                             int* __restrict__ deg) {
  int i = blockIdx.x * 256 + threadIdx.x;
  if (i >= ET) return;
  int d = (i < EE) ? ed[i] : i - EE;
  atomicAdd(&deg[d], 1);
}

// hierarchical scan, step 1: per-block local exclusive scan + block sums
__global__ __launch_bounds__(256) void k_scan1(const int* __restrict__ deg,
    int* __restrict__ rowp, int* __restrict__ bsum) {
  __shared__ int s[256];
  const int t = threadIdx.x;
  const int idx = blockIdx.x * 256 + t;
  const int v = (idx < NN) ? deg[idx] : 0;
  s[t] = v;
  __syncthreads();
  for (int off = 1; off < 256; off <<= 1) {
    int y = (t >= off) ? s[t - off] : 0;
    __syncthreads();
    s[t] += y;
    __syncthreads();
  }
  if (idx < NN) rowp[idx] = s[t] - v;       // local exclusive prefix
  if (t == 255) bsum[blockIdx.x] = s[255];  // block total
}

// step 2: one block scans the 196 block sums (exclusive, in place)
__global__ __launch_bounds__(256) void k_scan2(int* __restrict__ bsum) {
  __shared__ int s[256];
  const int t = threadIdx.x;
  const int v = (t < NBLK) ? bsum[t] : 0;
  s[t] = v;
  __syncthreads();
  for (int off = 1; off < 256; off <<= 1) {
    int y = (t >= off) ? s[t - off] : 0;
    __syncthreads();
    s[t] += y;
    __syncthreads();
  }
  if (t < NBLK) bsum[t] = s[t] - v;
}

// step 3: add block offsets; materialize cursor; rowp[NN] = ET (constant)
__global__ __launch_bounds__(256) void k_scan3(int* __restrict__ rowp,
    const int* __restrict__ bsum, int* __restrict__ cursor) {
  const int idx = blockIdx.x * 256 + threadIdx.x;
  if (idx < NN) {
    int r = rowp[idx] + bsum[blockIdx.x];
    rowp[idx] = r;
    cursor[idx] = r;
  }
  if (idx == 0) rowp[NN] = ET;
}

__global__ __launch_bounds__(256) void k_fill(const int* __restrict__ es,
    const int* __restrict__ ed, int* __restrict__ cursor, int* __restrict__ col) {
  int i = blockIdx.x * 256 + threadIdx.x;
  if (i >= ET) return;
  int s, d;
  if (i < EE) { s = es[i]; d = ed[i]; } else { s = d = i - EE; }
  int pos = atomicAdd(&cursor[d], 1);
  col[pos] = s;
}

// ---------------- Layer-1 aggregation (fused softmax+gather+bias+ELU) -----
// one wave per dst node; lane owns 4 cols (float4), head = lane>>3
__global__ __launch_bounds__(256) void k_agg1(const int* __restrict__ rowp,
    const int* __restrict__ col, const float* __restrict__ a_src,
    const float* __restrict__ a_dst, const float* __restrict__ h1,
    const float* __restrict__ b1, float* __restrict__ x2) {
  int node = (blockIdx.x * 256 + threadIdx.x) >> 6;
  int lane = threadIdx.x & 63;
  if (node >= NN) return;
  const int h = lane >> 3;
  const float ad = a_dst[node * NH + h];
  float4 num = {0.f, 0.f, 0.f, 0.f};
  float den = 0.f;  // replicated across the 8 lanes of each head
  const int beg = rowp[node], end = rowp[node + 1];
  for (int e = beg; e < end; e++) {
    int s = col[e];
    float w = __expf(lrelu(a_src[s * NH + h] + ad));
    den += w;
    float4 hv = ((const float4*)(h1 + (size_t)s * HID))[lane];
    num.x += w * hv.x;
    num.y += w * hv.y;
    num.z += w * hv.z;
    num.w += w * hv.w;
  }
  const float inv = 1.f / (den + 1e-16f);
  float4 b = ((const float4*)b1)[lane];
  float4 o;
  o.x = elu(num.x * inv + b.x);
  o.y = elu(num.y * inv + b.y);
  o.z = elu(num.z * inv + b.z);
  o.w = elu(num.w * inv + b.w);
  ((float4*)(x2 + (size_t)node * HID))[lane] = o;
}

// ---------------- GEMM 2: h2 = x2 @ W2 [N,64]; scalar att dots ------------
__global__ __launch_bounds__(256) void k_gemm2(const float* __restrict__ x2,
    const float* __restrict__ W2, const float* __restrict__ asw,
    const float* __restrict__ adw, float* __restrict__ h2,
    float* __restrict__ a_src2, float* __restrict__ a_dst2) {
  __shared__ float xs[16 * HID];
  const int tid = threadIdx.x;
  const int node0 = blockIdx.x << 4;
  for (int i = tid; i < 16 * HID; i += 256) xs[i] = x2[(size_t)node0 * HID + i];
  __syncthreads();
  const int lane = tid & 63, q = tid >> 6;
  float acc[4] = {0, 0, 0, 0};
  for (int k = 0; k < HID; k++) {
    float wv = W2[k * RP + lane];
#pragma unroll
    for (int j = 0; j < 4; j++) acc[j] += xs[(q * 4 + j) * HID + k] * wv;
  }
  const float as = asw[lane], ad = adw[lane];
#pragma unroll
  for (int j = 0; j < 4; j++) {
    int n = node0 + q * 4 + j;
    h2[(size_t)n * RP + lane] = acc[j];
    float vs = acc[j] * as, vd = acc[j] * ad;
#pragma unroll
    for (int dd = 32; dd; dd >>= 1) {
      vs += __shfl_down(vs, dd, 64);
      vd += __shfl_down(vd, dd, 64);
    }
    if (lane == 0) { a_src2[n] = vs; a_dst2[n] = vd; }
  }
}

// ---------------- Layer-2 aggregation (fused softmax+gather+bias) ---------
// one wave per dst node; lane owns 1 of 64 cols
__global__ __launch_bounds__(256) void k_agg2(const int* __restrict__ rowp,
    const int* __restrict__ col, const float* __restrict__ a_src2,
    const float* __restrict__ a_dst2, const float* __restrict__ h2,
    const float* __restrict__ b2, float* __restrict__ out) {
  int node = (blockIdx.x * 256 + threadIdx.x) >> 6;
  int lane = threadIdx.x & 63;
  if (node >= NN) return;
  const float ad = a_dst2[node];
  float num = 0.f, den = 0.f;
  const int beg = rowp[node], end = rowp[node + 1];
  for (int e = beg; e < end; e++) {
    int s = col[e];
    float w = __expf(lrelu(a_src2[s] + ad));
    den += w;
    num += w * h2[(size_t)s * RP + lane];
  }
  out[(size_t)node * RP + lane] = num / (den + 1e-16f) + b2[lane];
}

extern "C" void kernel_launch(void* const* d_in, const int* in_sizes, int n_in,
                              void* d_out, int out_size, void* d_ws, size_t ws_size,
                              hipStream_t stream) {
  const float* x   = (const float*)d_in[0];
  const float* W1  = (const float*)d_in[1];
  const float* a1s = (const float*)d_in[2];
  const float* a1d = (const float*)d_in[3];
  const float* b1  = (const float*)d_in[4];
  const float* W2  = (const float*)d_in[5];
  const float* a2s = (const float*)d_in[6];
  const float* a2d = (const float*)d_in[7];
  const float* b2  = (const float*)d_in[8];
  const int*   es  = (const int*)d_in[9];
  const int*   ed  = es + EE;
  float* out = (float*)d_out;

  // workspace layout (floats then ints)
  float* ws    = (float*)d_ws;
  float* h1    = ws;                          // N*256 (later reused as h2: N*64)
  float* x2    = h1 + (size_t)NN * HID;       // N*256
  float* asrc1 = x2 + (size_t)NN * HID;       // N*8
  float* adst1 = asrc1 + (size_t)NN * NH;     // N*8
  int*   deg   = (int*)(adst1 + (size_t)NN * NH);  // N
  int*   rowp  = deg + NN;                    // N+1
  int*   cursor = rowp + NN + 1;              // N
  int*   bsum  = cursor + NN;                 // NBLK
  int*   col   = bsum + NBLK;                 // ET
  // layer-2 reuses layer-1 storage
  float* h2    = h1;      // N*64
  float* asrc2 = asrc1;   // N
  float* adst2 = adst1;   // N

  hipMemsetAsync(deg, 0, (size_t)NN * sizeof(int), stream);

  // CSR build (independent of gemm1; cheap)
  k_deg<<<(ET + 255) / 256, 256, 0, stream>>>(ed, deg);
  k_scan1<<<NBLK, 256, 0, stream>>>(deg, rowp, bsum);
  k_scan2<<<1, 256, 0, stream>>>(bsum);
  k_scan3<<<NBLK, 256, 0, stream>>>(rowp, bsum, cursor);
  k_fill<<<(ET + 255) / 256, 256, 0, stream>>>(es, ed, cursor, col);

  // layer 1
  k_gemm1<<<NN / 8, 256, 0, stream>>>(x, W1, a1s, a1d, h1, asrc1, adst1);
  k_agg1<<<(NN * 64 + 255) / 256, 256, 0, stream>>>(rowp, col, asrc1, adst1, h1, b1, x2);

  // layer 2
  k_gemm2<<<NN / 16, 256, 0, stream>>>(x2, W2, a2s, a2d, h2, asrc2, adst2);
  k_agg2<<<(NN * 64 + 255) / 256, 256, 0, stream>>>(rowp, col, asrc2, adst2, h2, b2, out);
}

// Round 4
// 386.926 us; speedup vs baseline: 6.3414x; 1.0794x over previous
//
#include <hip/hip_runtime.h>

#define NN 50000      // nodes
#define EE 500000     // raw edges
#define ET 550000     // edges + self loops
#define EMB 128
#define HID 256
#define NH 8
#define RP 64
#define NBLK ((NN + 255) / 256)   // 196 scan blocks
#define G1_ROWS 32
#define G2_ROWS 32
#define EMBP (EMB + 4)   // padded LDS stride (bank-conflict break)
#define HIDP (HID + 4)

typedef unsigned short u16;

__device__ __forceinline__ float lrelu(float v) { return v > 0.f ? v : 0.2f * v; }
__device__ __forceinline__ float elu(float v) { return v > 0.f ? v : __expf(v) - 1.f; }
__device__ __forceinline__ u16 f2bf(float f) {
  unsigned int u = __float_as_uint(f);
  u += 0x7FFFu + ((u >> 16) & 1u);
  return (u16)(u >> 16);
}
__device__ __forceinline__ float bf2f(u16 b) {
  return __uint_as_float((unsigned int)b << 16);
}

// ---------- GEMM 1: h1 = x @ W1 [N,256] (bf16 out) + per-head att dots ----
// 32 rows x 256 cols per block; thread: 8 rows x 4 cols (float4 k-unroll)
__global__ __launch_bounds__(256) void k_gemm1(const float* __restrict__ x,
    const float* __restrict__ W1, const float* __restrict__ asw,
    const float* __restrict__ adw, u16* __restrict__ h1b,
    float* __restrict__ a_src, float* __restrict__ a_dst) {
  __shared__ float xs[G1_ROWS][EMBP];
  const int tid = threadIdx.x;
  const int node0 = blockIdx.x * G1_ROWS;
  for (int i = tid; i < G1_ROWS * (EMB / 4); i += 256) {
    int r = i >> 5, c4 = i & 31;
    float4 v = {0.f, 0.f, 0.f, 0.f};
    if (node0 + r < NN) v = ((const float4*)(x + (size_t)(node0 + r) * EMB))[c4];
    *((float4*)&xs[r][c4 * 4]) = v;
  }
  __syncthreads();
  const int cg = tid & 63;   // cols 4cg..4cg+3 (cg == lane)
  const int rg = tid >> 6;   // rows 8rg..8rg+7
  float acc[8][4] = {};
  const float4* W4 = (const float4*)W1;  // row stride 64 float4
  for (int k = 0; k < EMB; k += 4) {
    float4 w0 = W4[(k + 0) * 64 + cg];
    float4 w1 = W4[(k + 1) * 64 + cg];
    float4 w2 = W4[(k + 2) * 64 + cg];
    float4 w3 = W4[(k + 3) * 64 + cg];
#pragma unroll
    for (int r = 0; r < 8; r++) {
      float4 xv = *((const float4*)&xs[rg * 8 + r][k]);
      acc[r][0] += xv.x * w0.x + xv.y * w1.x + xv.z * w2.x + xv.w * w3.x;
      acc[r][1] += xv.x * w0.y + xv.y * w1.y + xv.z * w2.y + xv.w * w3.y;
      acc[r][2] += xv.x * w0.z + xv.y * w1.z + xv.z * w2.z + xv.w * w3.z;
      acc[r][3] += xv.x * w0.w + xv.y * w1.w + xv.z * w2.w + xv.w * w3.w;
    }
  }
  const float4 as4 = ((const float4*)asw)[cg];
  const float4 ad4 = ((const float4*)adw)[cg];
  const int h = cg >> 3;
#pragma unroll
  for (int r = 0; r < 8; r++) {
    int n = node0 + rg * 8 + r;
    bool valid = n < NN;
    ushort4 hb;
    hb.x = f2bf(acc[r][0]); hb.y = f2bf(acc[r][1]);
    hb.z = f2bf(acc[r][2]); hb.w = f2bf(acc[r][3]);
    if (valid) ((ushort4*)(h1b + (size_t)n * HID))[cg] = hb;
    float vs = acc[r][0] * as4.x + acc[r][1] * as4.y + acc[r][2] * as4.z + acc[r][3] * as4.w;
    float vd = acc[r][0] * ad4.x + acc[r][1] * ad4.y + acc[r][2] * ad4.z + acc[r][3] * ad4.w;
    vs += __shfl_down(vs, 4, 8); vs += __shfl_down(vs, 2, 8); vs += __shfl_down(vs, 1, 8);
    vd += __shfl_down(vd, 4, 8); vd += __shfl_down(vd, 2, 8); vd += __shfl_down(vd, 1, 8);
    if (valid && (cg & 7) == 0) {
      a_src[n * NH + h] = vs;
      a_dst[n * NH + h] = vd;
    }
  }
}

// ---------------- CSR build (by dst) --------------------------------------
__global__ __launch_bounds__(256) void k_deg(const int* __restrict__ ed,
                                             int* __restrict__ deg) {
  int i = blockIdx.x * 256 + threadIdx.x;
  if (i >= ET) return;
  int d = (i < EE) ? ed[i] : i - EE;
  atomicAdd(&deg[d], 1);
}

__global__ __launch_bounds__(256) void k_scan1(const int* __restrict__ deg,
    int* __restrict__ rowp, int* __restrict__ bsum) {
  __shared__ int s[256];
  const int t = threadIdx.x;
  const int idx = blockIdx.x * 256 + t;
  const int v = (idx < NN) ? deg[idx] : 0;
  s[t] = v;
  __syncthreads();
  for (int off = 1; off < 256; off <<= 1) {
    int y = (t >= off) ? s[t - off] : 0;
    __syncthreads();
    s[t] += y;
    __syncthreads();
  }
  if (idx < NN) rowp[idx] = s[t] - v;
  if (t == 255) bsum[blockIdx.x] = s[255];
}

__global__ __launch_bounds__(256) void k_scan2(int* __restrict__ bsum) {
  __shared__ int s[256];
  const int t = threadIdx.x;
  const int v = (t < NBLK) ? bsum[t] : 0;
  s[t] = v;
  __syncthreads();
  for (int off = 1; off < 256; off <<= 1) {
    int y = (t >= off) ? s[t - off] : 0;
    __syncthreads();
    s[t] += y;
    __syncthreads();
  }
  if (t < NBLK) bsum[t] = s[t] - v;
}

__global__ __launch_bounds__(256) void k_scan3(int* __restrict__ rowp,
    const int* __restrict__ bsum, int* __restrict__ cursor) {
  const int idx = blockIdx.x * 256 + threadIdx.x;
  if (idx < NN) {
    int r = rowp[idx] + bsum[blockIdx.x];
    rowp[idx] = r;
    cursor[idx] = r;
  }
  if (idx == 0) rowp[NN] = ET;
}

__global__ __launch_bounds__(256) void k_fill(const int* __restrict__ es,
    const int* __restrict__ ed, int* __restrict__ cursor, int* __restrict__ col) {
  int i = blockIdx.x * 256 + threadIdx.x;
  if (i >= ET) return;
  int s, d;
  if (i < EE) { s = es[i]; d = ed[i]; } else { s = d = i - EE; }
  int pos = atomicAdd(&cursor[d], 1);
  col[pos] = s;
}

// ---------- Layer-1 aggregation: softmax+gather(bf16)+bias+ELU ------------
// one wave per dst node; lane owns 4 cols (ushort4 = 8B), head = lane>>3
__global__ __launch_bounds__(256) void k_agg1(const int* __restrict__ rowp,
    const int* __restrict__ col, const float* __restrict__ a_src,
    const float* __restrict__ a_dst, const u16* __restrict__ h1b,
    const float* __restrict__ b1, float* __restrict__ x2) {
  int node = (blockIdx.x * 256 + threadIdx.x) >> 6;
  int lane = threadIdx.x & 63;
  if (node >= NN) return;
  const int h = lane >> 3;
  const float ad = a_dst[node * NH + h];
  float4 num = {0.f, 0.f, 0.f, 0.f};
  float den = 0.f;
  const int beg = rowp[node], end = rowp[node + 1];
  for (int e = beg; e < end; e++) {
    int s = col[e];
    float w = __expf(lrelu(a_src[s * NH + h] + ad));
    den += w;
    ushort4 hv = ((const ushort4*)(h1b + (size_t)s * HID))[lane];
    num.x += w * bf2f(hv.x);
    num.y += w * bf2f(hv.y);
    num.z += w * bf2f(hv.z);
    num.w += w * bf2f(hv.w);
  }
  const float inv = 1.f / (den + 1e-16f);
  float4 b = ((const float4*)b1)[lane];
  float4 o;
  o.x = elu(num.x * inv + b.x);
  o.y = elu(num.y * inv + b.y);
  o.z = elu(num.z * inv + b.z);
  o.w = elu(num.w * inv + b.w);
  ((float4*)(x2 + (size_t)node * HID))[lane] = o;
}

// ---------- GEMM 2: h2 = x2 @ W2 [N,64] (bf16 out) + scalar att dots ------
// 32 rows x 64 cols per block; thread: 2 rows x 4 cols
__global__ __launch_bounds__(256) void k_gemm2(const float* __restrict__ x2,
    const float* __restrict__ W2, const float* __restrict__ asw,
    const float* __restrict__ adw, u16* __restrict__ h2b,
    float* __restrict__ a_src2, float* __restrict__ a_dst2) {
  __shared__ float xs[G2_ROWS][HIDP];
  const int tid = threadIdx.x;
  const int node0 = blockIdx.x * G2_ROWS;
  for (int i = tid; i < G2_ROWS * (HID / 4); i += 256) {
    int r = i >> 6, c4 = i & 63;
    float4 v = {0.f, 0.f, 0.f, 0.f};
    if (node0 + r < NN) v = ((const float4*)(x2 + (size_t)(node0 + r) * HID))[c4];
    *((float4*)&xs[r][c4 * 4]) = v;
  }
  __syncthreads();
  const int ct = tid & 15;   // cols 4ct..4ct+3
  const int rg = tid >> 4;   // rows 2rg..2rg+1
  float acc[2][4] = {};
  const float4* W4 = (const float4*)W2;  // row stride 16 float4
  for (int k = 0; k < HID; k += 4) {
    float4 w0 = W4[(k + 0) * 16 + ct];
    float4 w1 = W4[(k + 1) * 16 + ct];
    float4 w2 = W4[(k + 2) * 16 + ct];
    float4 w3 = W4[(k + 3) * 16 + ct];
#pragma unroll
    for (int r = 0; r < 2; r++) {
      float4 xv = *((const float4*)&xs[rg * 2 + r][k]);
      acc[r][0] += xv.x * w0.x + xv.y * w1.x + xv.z * w2.x + xv.w * w3.x;
      acc[r][1] += xv.x * w0.y + xv.y * w1.y + xv.z * w2.y + xv.w * w3.y;
      acc[r][2] += xv.x * w0.z + xv.y * w1.z + xv.z * w2.z + xv.w * w3.z;
      acc[r][3] += xv.x * w0.w + xv.y * w1.w + xv.z * w2.w + xv.w * w3.w;
    }
  }
  const float4 as4 = ((const float4*)asw)[ct];
  const float4 ad4 = ((const float4*)adw)[ct];
#pragma unroll
  for (int r = 0; r < 2; r++) {
    int n = node0 + rg * 2 + r;
    bool valid = n < NN;
    ushort4 hb;
    hb.x = f2bf(acc[r][0]); hb.y = f2bf(acc[r][1]);
    hb.z = f2bf(acc[r][2]); hb.w = f2bf(acc[r][3]);
    if (valid) ((ushort4*)(h2b + (size_t)n * RP))[ct] = hb;
    float vs = acc[r][0] * as4.x + acc[r][1] * as4.y + acc[r][2] * as4.z + acc[r][3] * as4.w;
    float vd = acc[r][0] * ad4.x + acc[r][1] * ad4.y + acc[r][2] * ad4.z + acc[r][3] * ad4.w;
    vs += __shfl_down(vs, 8, 16); vs += __shfl_down(vs, 4, 16);
    vs += __shfl_down(vs, 2, 16); vs += __shfl_down(vs, 1, 16);
    vd += __shfl_down(vd, 8, 16); vd += __shfl_down(vd, 4, 16);
    vd += __shfl_down(vd, 2, 16); vd += __shfl_down(vd, 1, 16);
    if (valid && ct == 0) { a_src2[n] = vs; a_dst2[n] = vd; }
  }
}

// ---------- Layer-2 aggregation: softmax+gather(bf16)+bias ----------------
__global__ __launch_bounds__(256) void k_agg2(const int* __restrict__ rowp,
    const int* __restrict__ col, const float* __restrict__ a_src2,
    const float* __restrict__ a_dst2, const u16* __restrict__ h2b,
    const float* __restrict__ b2, float* __restrict__ out) {
  int node = (blockIdx.x * 256 + threadIdx.x) >> 6;
  int lane = threadIdx.x & 63;
  if (node >= NN) return;
  const float ad = a_dst2[node];
  float num = 0.f, den = 0.f;
  const int beg = rowp[node], end = rowp[node + 1];
  for (int e = beg; e < end; e++) {
    int s = col[e];
    float w = __expf(lrelu(a_src2[s] + ad));
    den += w;
    num += w * bf2f(h2b[(size_t)s * RP + lane]);
  }
  out[(size_t)node * RP + lane] = num / (den + 1e-16f) + b2[lane];
}

extern "C" void kernel_launch(void* const* d_in, const int* in_sizes, int n_in,
                              void* d_out, int out_size, void* d_ws, size_t ws_size,
                              hipStream_t stream) {
  const float* x   = (const float*)d_in[0];
  const float* W1  = (const float*)d_in[1];
  const float* a1s = (const float*)d_in[2];
  const float* a1d = (const float*)d_in[3];
  const float* b1  = (const float*)d_in[4];
  const float* W2  = (const float*)d_in[5];
  const float* a2s = (const float*)d_in[6];
  const float* a2d = (const float*)d_in[7];
  const float* b2  = (const float*)d_in[8];
  const int*   es  = (const int*)d_in[9];
  const int*   ed  = es + EE;
  float* out = (float*)d_out;

  // workspace layout
  u16*   h1b   = (u16*)d_ws;                        // N*256 bf16 (reused as h2b)
  float* x2    = (float*)(h1b + (size_t)NN * HID);  // N*256 f32
  float* asrc1 = x2 + (size_t)NN * HID;             // N*8
  float* adst1 = asrc1 + (size_t)NN * NH;           // N*8
  int*   deg   = (int*)(adst1 + (size_t)NN * NH);   // N
  int*   rowp  = deg + NN;                          // N+1
  int*   cursor = rowp + NN + 1;                    // N
  int*   bsum  = cursor + NN;                       // NBLK
  int*   col   = bsum + NBLK;                       // ET
  // layer-2 reuses layer-1 storage
  u16*   h2b   = h1b;     // N*64 bf16
  float* asrc2 = asrc1;   // N
  float* adst2 = adst1;   // N

  hipMemsetAsync(deg, 0, (size_t)NN * sizeof(int), stream);

  // CSR build
  k_deg<<<(ET + 255) / 256, 256, 0, stream>>>(ed, deg);
  k_scan1<<<NBLK, 256, 0, stream>>>(deg, rowp, bsum);
  k_scan2<<<1, 256, 0, stream>>>(bsum);
  k_scan3<<<NBLK, 256, 0, stream>>>(rowp, bsum, cursor);
  k_fill<<<(ET + 255) / 256, 256, 0, stream>>>(es, ed, cursor, col);

  // layer 1
  k_gemm1<<<(NN + G1_ROWS - 1) / G1_ROWS, 256, 0, stream>>>(x, W1, a1s, a1d, h1b, asrc1, adst1);
  k_agg1<<<(NN * 64 + 255) / 256, 256, 0, stream>>>(rowp, col, asrc1, adst1, h1b, b1, x2);

  // layer 2
  k_gemm2<<<(NN + G2_ROWS - 1) / G2_ROWS, 256, 0, stream>>>(x2, W2, a2s, a2d, h2b, asrc2, adst2);
  k_agg2<<<(NN * 64 + 255) / 256, 256, 0, stream>>>(rowp, col, asrc2, adst2, h2b, b2, out);
}

// Round 5
// 310.763 us; speedup vs baseline: 7.8956x; 1.2451x over previous
//
#include <hip/hip_runtime.h>

#define NN 50000      // nodes
#define EE 500000     // raw edges
#define ET 550000     // edges + self loops
#define EMB 128
#define HID 256
#define NH 8
#define RP 64
#define NBLK ((NN + 255) / 256)   // 196 scan blocks
#define G1_ROWS 32
#define G2_ROWS 32
#define EMBP (EMB + 4)   // padded LDS stride
#define HIDP (HID + 4)
#define G1_BLOCKS ((NN + G1_ROWS - 1) / G1_ROWS)   // 1563
#define FILL_BLOCKS ((ET + 255) / 256)             // 2149

typedef unsigned short u16;

__device__ __forceinline__ float lrelu(float v) { return v > 0.f ? v : 0.2f * v; }
__device__ __forceinline__ float elu(float v) { return v > 0.f ? v : __expf(v) - 1.f; }
__device__ __forceinline__ u16 f2bf(float f) {
  unsigned int u = __float_as_uint(f);
  u += 0x7FFFu + ((u >> 16) & 1u);
  return (u16)(u >> 16);
}
__device__ __forceinline__ float bfl(unsigned int u) {  // low bf16 of dword
  return __uint_as_float(u << 16);
}
__device__ __forceinline__ float bfh(unsigned int u) {  // high bf16 of dword
  return __uint_as_float(u & 0xFFFF0000u);
}

// ---------- GEMM 1 (+ fused CSR fill): h1 = x @ W1 (bf16) + att dots ------
// blocks [0, G1_BLOCKS): gemm tile 32 rows x 256 cols; thread: 8r x 4c
// blocks [G1_BLOCKS, +FILL_BLOCKS): CSR fill (independent work, overlapped)
__global__ __launch_bounds__(256) void k_gemm1_fill(const float* __restrict__ x,
    const float* __restrict__ W1, const float* __restrict__ asw,
    const float* __restrict__ adw, u16* __restrict__ h1b,
    float* __restrict__ a_src, float* __restrict__ a_dst,
    const int* __restrict__ es, const int* __restrict__ ed,
    int* __restrict__ cursor, int* __restrict__ col) {
  __shared__ float xs[G1_ROWS][EMBP];
  const int tid = threadIdx.x;
  if (blockIdx.x >= G1_BLOCKS) {
    // ---- CSR fill body ----
    int i = (blockIdx.x - G1_BLOCKS) * 256 + tid;
    if (i < ET) {
      int s, d;
      if (i < EE) { s = es[i]; d = ed[i]; } else { s = d = i - EE; }
      int pos = atomicAdd(&cursor[d], 1);
      col[pos] = s;
    }
    return;
  }
  // ---- GEMM body ----
  const int node0 = blockIdx.x * G1_ROWS;
  for (int i = tid; i < G1_ROWS * (EMB / 4); i += 256) {
    int r = i >> 5, c4 = i & 31;
    float4 v = {0.f, 0.f, 0.f, 0.f};
    if (node0 + r < NN) v = ((const float4*)(x + (size_t)(node0 + r) * EMB))[c4];
    *((float4*)&xs[r][c4 * 4]) = v;
  }
  __syncthreads();
  const int cg = tid & 63;
  const int rg = tid >> 6;
  float acc[8][4] = {};
  const float4* W4 = (const float4*)W1;
  for (int k = 0; k < EMB; k += 4) {
    float4 w0 = W4[(k + 0) * 64 + cg];
    float4 w1 = W4[(k + 1) * 64 + cg];
    float4 w2 = W4[(k + 2) * 64 + cg];
    float4 w3 = W4[(k + 3) * 64 + cg];
#pragma unroll
    for (int r = 0; r < 8; r++) {
      float4 xv = *((const float4*)&xs[rg * 8 + r][k]);
      acc[r][0] += xv.x * w0.x + xv.y * w1.x + xv.z * w2.x + xv.w * w3.x;
      acc[r][1] += xv.x * w0.y + xv.y * w1.y + xv.z * w2.y + xv.w * w3.y;
      acc[r][2] += xv.x * w0.z + xv.y * w1.z + xv.z * w2.z + xv.w * w3.z;
      acc[r][3] += xv.x * w0.w + xv.y * w1.w + xv.z * w2.w + xv.w * w3.w;
    }
  }
  const float4 as4 = ((const float4*)asw)[cg];
  const float4 ad4 = ((const float4*)adw)[cg];
  const int h = cg >> 3;
#pragma unroll
  for (int r = 0; r < 8; r++) {
    int n = node0 + rg * 8 + r;
    bool valid = n < NN;
    ushort4 hb;
    hb.x = f2bf(acc[r][0]); hb.y = f2bf(acc[r][1]);
    hb.z = f2bf(acc[r][2]); hb.w = f2bf(acc[r][3]);
    if (valid) ((ushort4*)(h1b + (size_t)n * HID))[cg] = hb;
    float vs = acc[r][0] * as4.x + acc[r][1] * as4.y + acc[r][2] * as4.z + acc[r][3] * as4.w;
    float vd = acc[r][0] * ad4.x + acc[r][1] * ad4.y + acc[r][2] * ad4.z + acc[r][3] * ad4.w;
    vs += __shfl_down(vs, 4, 8); vs += __shfl_down(vs, 2, 8); vs += __shfl_down(vs, 1, 8);
    vd += __shfl_down(vd, 4, 8); vd += __shfl_down(vd, 2, 8); vd += __shfl_down(vd, 1, 8);
    if (valid && (cg & 7) == 0) {
      a_src[n * NH + h] = vs;
      a_dst[n * NH + h] = vd;
    }
  }
}

// ---------------- CSR build (by dst) --------------------------------------
__global__ __launch_bounds__(256) void k_deg(const int* __restrict__ ed,
                                             int* __restrict__ deg) {
  int i = blockIdx.x * 256 + threadIdx.x;
  if (i >= ET) return;
  int d = (i < EE) ? ed[i] : i - EE;
  atomicAdd(&deg[d], 1);
}

__global__ __launch_bounds__(256) void k_scan1(const int* __restrict__ deg,
    int* __restrict__ rowp, int* __restrict__ bsum) {
  __shared__ int s[256];
  const int t = threadIdx.x;
  const int idx = blockIdx.x * 256 + t;
  const int v = (idx < NN) ? deg[idx] : 0;
  s[t] = v;
  __syncthreads();
  for (int off = 1; off < 256; off <<= 1) {
    int y = (t >= off) ? s[t - off] : 0;
    __syncthreads();
    s[t] += y;
    __syncthreads();
  }
  if (idx < NN) rowp[idx] = s[t] - v;
  if (t == 255) bsum[blockIdx.x] = s[255];
}

__global__ __launch_bounds__(256) void k_scan2(int* __restrict__ bsum) {
  __shared__ int s[256];
  const int t = threadIdx.x;
  const int v = (t < NBLK) ? bsum[t] : 0;
  s[t] = v;
  __syncthreads();
  for (int off = 1; off < 256; off <<= 1) {
    int y = (t >= off) ? s[t - off] : 0;
    __syncthreads();
    s[t] += y;
    __syncthreads();
  }
  if (t < NBLK) bsum[t] = s[t] - v;
}

__global__ __launch_bounds__(256) void k_scan3(int* __restrict__ rowp,
    const int* __restrict__ bsum, int* __restrict__ cursor) {
  const int idx = blockIdx.x * 256 + threadIdx.x;
  if (idx < NN) {
    int r = rowp[idx] + bsum[blockIdx.x];
    rowp[idx] = r;
    cursor[idx] = r;
  }
  if (idx == 0) rowp[NN] = ET;
}

// ---------- Layer-1 aggregation: half-wave edge-parallel ------------------
// wave = 1 dst node; lanes 0-31 even edges, 32-63 odd edges;
// lane covers 8 cols (uint4 = 8 bf16); combine halves via shfl_xor(32)
__global__ __launch_bounds__(256) void k_agg1(const int* __restrict__ rowp,
    const int* __restrict__ col, const float* __restrict__ a_src,
    const float* __restrict__ a_dst, const u16* __restrict__ h1b,
    const float* __restrict__ b1, float* __restrict__ x2) {
  int node = (blockIdx.x * 256 + threadIdx.x) >> 6;
  if (node >= NN) return;
  const int lane = threadIdx.x & 63;
  const int half = lane >> 5;
  const int hl = lane & 31;     // owns cols 8*hl .. 8*hl+7
  const int h = hl >> 2;        // head
  const float ad = a_dst[node * NH + h];
  float num[8] = {};
  float den = 0.f;
  const int beg = rowp[node], end = rowp[node + 1];
  int e = beg + half;
  int sn = (e < end) ? col[e] : 0;
  for (; e < end; e += 2) {
    int s = sn;
    if (e + 2 < end) sn = col[e + 2];
    float w = __expf(lrelu(a_src[s * NH + h] + ad));
    uint4 hv = ((const uint4*)(h1b + (size_t)s * HID))[hl];
    den += w;
    num[0] += w * bfl(hv.x); num[1] += w * bfh(hv.x);
    num[2] += w * bfl(hv.y); num[3] += w * bfh(hv.y);
    num[4] += w * bfl(hv.z); num[5] += w * bfh(hv.z);
    num[6] += w * bfl(hv.w); num[7] += w * bfh(hv.w);
  }
  den += __shfl_xor(den, 32, 64);
#pragma unroll
  for (int j = 0; j < 8; j++) num[j] += __shfl_xor(num[j], 32, 64);
  if (half == 0) {
    const float inv = 1.f / (den + 1e-16f);
    const float4 b0 = ((const float4*)(b1 + hl * 8))[0];
    const float4 b1v = ((const float4*)(b1 + hl * 8))[1];
    float4 o0, o1;
    o0.x = elu(num[0] * inv + b0.x);
    o0.y = elu(num[1] * inv + b0.y);
    o0.z = elu(num[2] * inv + b0.z);
    o0.w = elu(num[3] * inv + b0.w);
    o1.x = elu(num[4] * inv + b1v.x);
    o1.y = elu(num[5] * inv + b1v.y);
    o1.z = elu(num[6] * inv + b1v.z);
    o1.w = elu(num[7] * inv + b1v.w);
    float* po = x2 + (size_t)node * HID + hl * 8;
    ((float4*)po)[0] = o0;
    ((float4*)po)[1] = o1;
  }
}

// ---------- GEMM 2: h2 = x2 @ W2 [N,64] (bf16 out) + scalar att dots ------
__global__ __launch_bounds__(256) void k_gemm2(const float* __restrict__ x2,
    const float* __restrict__ W2, const float* __restrict__ asw,
    const float* __restrict__ adw, u16* __restrict__ h2b,
    float* __restrict__ a_src2, float* __restrict__ a_dst2) {
  __shared__ float xs[G2_ROWS][HIDP];
  const int tid = threadIdx.x;
  const int node0 = blockIdx.x * G2_ROWS;
  for (int i = tid; i < G2_ROWS * (HID / 4); i += 256) {
    int r = i >> 6, c4 = i & 63;
    float4 v = {0.f, 0.f, 0.f, 0.f};
    if (node0 + r < NN) v = ((const float4*)(x2 + (size_t)(node0 + r) * HID))[c4];
    *((float4*)&xs[r][c4 * 4]) = v;
  }
  __syncthreads();
  const int ct = tid & 15;
  const int rg = tid >> 4;
  float acc[2][4] = {};
  const float4* W4 = (const float4*)W2;
  for (int k = 0; k < HID; k += 4) {
    float4 w0 = W4[(k + 0) * 16 + ct];
    float4 w1 = W4[(k + 1) * 16 + ct];
    float4 w2 = W4[(k + 2) * 16 + ct];
    float4 w3 = W4[(k + 3) * 16 + ct];
#pragma unroll
    for (int r = 0; r < 2; r++) {
      float4 xv = *((const float4*)&xs[rg * 2 + r][k]);
      acc[r][0] += xv.x * w0.x + xv.y * w1.x + xv.z * w2.x + xv.w * w3.x;
      acc[r][1] += xv.x * w0.y + xv.y * w1.y + xv.z * w2.y + xv.w * w3.y;
      acc[r][2] += xv.x * w0.z + xv.y * w1.z + xv.z * w2.z + xv.w * w3.z;
      acc[r][3] += xv.x * w0.w + xv.y * w1.w + xv.z * w2.w + xv.w * w3.w;
    }
  }
  const float4 as4 = ((const float4*)asw)[ct];
  const float4 ad4 = ((const float4*)adw)[ct];
#pragma unroll
  for (int r = 0; r < 2; r++) {
    int n = node0 + rg * 2 + r;
    bool valid = n < NN;
    ushort4 hb;
    hb.x = f2bf(acc[r][0]); hb.y = f2bf(acc[r][1]);
    hb.z = f2bf(acc[r][2]); hb.w = f2bf(acc[r][3]);
    if (valid) ((ushort4*)(h2b + (size_t)n * RP))[ct] = hb;
    float vs = acc[r][0] * as4.x + acc[r][1] * as4.y + acc[r][2] * as4.z + acc[r][3] * as4.w;
    float vd = acc[r][0] * ad4.x + acc[r][1] * ad4.y + acc[r][2] * ad4.z + acc[r][3] * ad4.w;
    vs += __shfl_down(vs, 8, 16); vs += __shfl_down(vs, 4, 16);
    vs += __shfl_down(vs, 2, 16); vs += __shfl_down(vs, 1, 16);
    vd += __shfl_down(vd, 8, 16); vd += __shfl_down(vd, 4, 16);
    vd += __shfl_down(vd, 2, 16); vd += __shfl_down(vd, 1, 16);
    if (valid && ct == 0) { a_src2[n] = vs; a_dst2[n] = vd; }
  }
}

// ---------- Layer-2 aggregation: quarter-wave edge-parallel ---------------
// wave = 1 dst node; 4 edges/iter; lane covers 4 cols (uint2 = 4 bf16)
__global__ __launch_bounds__(256) void k_agg2(const int* __restrict__ rowp,
    const int* __restrict__ col, const float* __restrict__ a_src2,
    const float* __restrict__ a_dst2, const u16* __restrict__ h2b,
    const float* __restrict__ b2, float* __restrict__ out) {
  int node = (blockIdx.x * 256 + threadIdx.x) >> 6;
  if (node >= NN) return;
  const int lane = threadIdx.x & 63;
  const int q = lane >> 4;
  const int ql = lane & 15;     // owns cols 4*ql .. 4*ql+3
  const float ad = a_dst2[node];
  float num[4] = {};
  float den = 0.f;
  const int beg = rowp[node], end = rowp[node + 1];
  int e = beg + q;
  int sn = (e < end) ? col[e] : 0;
  for (; e < end; e += 4) {
    int s = sn;
    if (e + 4 < end) sn = col[e + 4];
    float w = __expf(lrelu(a_src2[s] + ad));
    uint2 hv = ((const uint2*)(h2b + (size_t)s * RP))[ql];
    den += w;
    num[0] += w * bfl(hv.x); num[1] += w * bfh(hv.x);
    num[2] += w * bfl(hv.y); num[3] += w * bfh(hv.y);
  }
  den += __shfl_xor(den, 16, 64);
  den += __shfl_xor(den, 32, 64);
#pragma unroll
  for (int j = 0; j < 4; j++) {
    num[j] += __shfl_xor(num[j], 16, 64);
    num[j] += __shfl_xor(num[j], 32, 64);
  }
  if (q == 0) {
    const float inv = 1.f / (den + 1e-16f);
    const float4 b = ((const float4*)(b2 + ql * 4))[0];
    float4 o;
    o.x = num[0] * inv + b.x;
    o.y = num[1] * inv + b.y;
    o.z = num[2] * inv + b.z;
    o.w = num[3] * inv + b.w;
    ((float4*)(out + (size_t)node * RP + ql * 4))[0] = o;
  }
}

extern "C" void kernel_launch(void* const* d_in, const int* in_sizes, int n_in,
                              void* d_out, int out_size, void* d_ws, size_t ws_size,
                              hipStream_t stream) {
  const float* x   = (const float*)d_in[0];
  const float* W1  = (const float*)d_in[1];
  const float* a1s = (const float*)d_in[2];
  const float* a1d = (const float*)d_in[3];
  const float* b1  = (const float*)d_in[4];
  const float* W2  = (const float*)d_in[5];
  const float* a2s = (const float*)d_in[6];
  const float* a2d = (const float*)d_in[7];
  const float* b2  = (const float*)d_in[8];
  const int*   es  = (const int*)d_in[9];
  const int*   ed  = es + EE;
  float* out = (float*)d_out;

  // workspace layout
  u16*   h1b   = (u16*)d_ws;                        // N*256 bf16 (reused as h2b)
  float* x2    = (float*)(h1b + (size_t)NN * HID);  // N*256 f32
  float* asrc1 = x2 + (size_t)NN * HID;             // N*8
  float* adst1 = asrc1 + (size_t)NN * NH;           // N*8
  int*   deg   = (int*)(adst1 + (size_t)NN * NH);   // N
  int*   rowp  = deg + NN;                          // N+1
  int*   cursor = rowp + NN + 1;                    // N
  int*   bsum  = cursor + NN;                       // NBLK
  int*   col   = bsum + NBLK;                       // ET
  u16*   h2b   = h1b;
  float* asrc2 = asrc1;
  float* adst2 = adst1;

  hipMemsetAsync(deg, 0, (size_t)NN * sizeof(int), stream);

  // CSR degree + scan
  k_deg<<<(ET + 255) / 256, 256, 0, stream>>>(ed, deg);
  k_scan1<<<NBLK, 256, 0, stream>>>(deg, rowp, bsum);
  k_scan2<<<1, 256, 0, stream>>>(bsum);
  k_scan3<<<NBLK, 256, 0, stream>>>(rowp, bsum, cursor);

  // GEMM1 fused with CSR fill (independent; overlap in HW)
  k_gemm1_fill<<<G1_BLOCKS + FILL_BLOCKS, 256, 0, stream>>>(
      x, W1, a1s, a1d, h1b, asrc1, adst1, es, ed, cursor, col);

  k_agg1<<<(NN * 64 + 255) / 256, 256, 0, stream>>>(rowp, col, asrc1, adst1, h1b, b1, x2);
  k_gemm2<<<(NN + G2_ROWS - 1) / G2_ROWS, 256, 0, stream>>>(x2, W2, a2s, a2d, h2b, asrc2, adst2);
  k_agg2<<<(NN * 64 + 255) / 256, 256, 0, stream>>>(rowp, col, asrc2, adst2, h2b, b2, out);
}

// Round 6
// 304.776 us; speedup vs baseline: 8.0507x; 1.0196x over previous
//
#include <hip/hip_runtime.h>

#define NN 50000      // nodes
#define EE 500000     // raw edges
#define ET 550000     // edges + self loops
#define EMB 128
#define HID 256
#define NH 8
#define RP 64
#define NBLK ((NN + 255) / 256)   // 196 scan blocks
#define G2_ROWS 32
#define HIDP (HID + 4)
#define G1M_BLOCKS (NN / 16)                       // 3125 MFMA m-tiles
#define FILL_BLOCKS ((ET + 255) / 256)             // 2149
#define DEG_BLOCKS ((ET + 255) / 256)              // 2149
#define BP_BLOCKS 16                               // W1 bf16 frag-prep blocks

typedef unsigned short u16;
typedef __attribute__((ext_vector_type(8))) short bf16x8;
typedef __attribute__((ext_vector_type(4))) float f32x4;

__device__ __forceinline__ float lrelu(float v) { return v > 0.f ? v : 0.2f * v; }
__device__ __forceinline__ float elu(float v) { return v > 0.f ? v : __expf(v) - 1.f; }
__device__ __forceinline__ u16 f2bf(float f) {
  unsigned int u = __float_as_uint(f);
  u += 0x7FFFu + ((u >> 16) & 1u);
  return (u16)(u >> 16);
}
__device__ __forceinline__ float bfl(unsigned int u) { return __uint_as_float(u << 16); }
__device__ __forceinline__ float bfh(unsigned int u) { return __uint_as_float(u & 0xFFFF0000u); }

// ---------- k_pre: degree count + W1 -> bf16 B-fragment layout ------------
// blocks [0, DEG_BLOCKS): degree atomics
// blocks [DEG_BLOCKS, +BP_BLOCKS): Bbuf[kt*16+nt][lane][j] = bf16(W1[kt*32+quad*8+j][nt*16+qr])
__global__ __launch_bounds__(256) void k_pre(const int* __restrict__ ed,
    int* __restrict__ deg, const float* __restrict__ W1, u16* __restrict__ Bbuf) {
  const int tid = threadIdx.x;
  if (blockIdx.x < DEG_BLOCKS) {
    int i = blockIdx.x * 256 + tid;
    if (i < ET) {
      int d = (i < EE) ? ed[i] : i - EE;
      atomicAdd(&deg[d], 1);
    }
    return;
  }
  // W1 frag-prep: 16 blocks x 4 waves = 64 (kt,nt) tiles
  const int tile = (blockIdx.x - DEG_BLOCKS) * 4 + (tid >> 6);  // kt*16+nt
  const int l = tid & 63;
  const int quad = l >> 4, qr = l & 15;
  const int kt = tile >> 4, nt = tile & 15;
  const float* src = W1 + (size_t)(kt * 32 + quad * 8) * HID + nt * 16 + qr;
  unsigned int p[4];
#pragma unroll
  for (int jp = 0; jp < 4; jp++) {
    u16 lo = f2bf(src[(2 * jp + 0) * HID]);
    u16 hi = f2bf(src[(2 * jp + 1) * HID]);
    p[jp] = (unsigned int)lo | ((unsigned int)hi << 16);
  }
  uint4 v = {p[0], p[1], p[2], p[3]};
  ((uint4*)Bbuf)[tile * 64 + l] = v;
}

// ---------------- scans ---------------------------------------------------
__global__ __launch_bounds__(256) void k_scan1(const int* __restrict__ deg,
    int* __restrict__ rowp, int* __restrict__ bsum) {
  __shared__ int s[256];
  const int t = threadIdx.x;
  const int idx = blockIdx.x * 256 + t;
  const int v = (idx < NN) ? deg[idx] : 0;
  s[t] = v;
  __syncthreads();
  for (int off = 1; off < 256; off <<= 1) {
    int y = (t >= off) ? s[t - off] : 0;
    __syncthreads();
    s[t] += y;
    __syncthreads();
  }
  if (idx < NN) rowp[idx] = s[t] - v;
  if (t == 255) bsum[blockIdx.x] = s[255];
}

__global__ __launch_bounds__(256) void k_scan2(int* __restrict__ bsum) {
  __shared__ int s[256];
  const int t = threadIdx.x;
  const int v = (t < NBLK) ? bsum[t] : 0;
  s[t] = v;
  __syncthreads();
  for (int off = 1; off < 256; off <<= 1) {
    int y = (t >= off) ? s[t - off] : 0;
    __syncthreads();
    s[t] += y;
    __syncthreads();
  }
  if (t < NBLK) bsum[t] = s[t] - v;
}

__global__ __launch_bounds__(256) void k_scan3(int* __restrict__ rowp,
    const int* __restrict__ bsum, int* __restrict__ cursor) {
  const int idx = blockIdx.x * 256 + threadIdx.x;
  if (idx < NN) {
    int r = rowp[idx] + bsum[blockIdx.x];
    rowp[idx] = r;
    cursor[idx] = r;
  }
  if (idx == 0) rowp[NN] = ET;
}

// ---------- GEMM 1 via MFMA bf16 (+ fused CSR fill) -----------------------
// blocks [0, G1M_BLOCKS): 16 nodes/block; wave w covers cols [64w,64w+64)
//   A[m=lane&15][k=quad*8+j] from x (f32->bf16 inflight); B from Bbuf frags.
//   C/D: col=lane&15, row=quad*4+reg.
// blocks [G1M_BLOCKS, +FILL_BLOCKS): CSR fill.
__global__ __launch_bounds__(256) void k_gemm1m_fill(const float* __restrict__ x,
    const u16* __restrict__ Bbuf, const float* __restrict__ asw,
    const float* __restrict__ adw, u16* __restrict__ h1b,
    float* __restrict__ a_src, float* __restrict__ a_dst,
    const int* __restrict__ es, const int* __restrict__ ed,
    int* __restrict__ cursor, int* __restrict__ col) {
  const int tid = threadIdx.x;
  if (blockIdx.x >= G1M_BLOCKS) {
    int i = (blockIdx.x - G1M_BLOCKS) * 256 + tid;
    if (i < ET) {
      int s, d;
      if (i < EE) { s = es[i]; d = ed[i]; } else { s = d = i - EE; }
      int pos = atomicAdd(&cursor[d], 1);
      col[pos] = s;
    }
    return;
  }
  const int w = tid >> 6, l = tid & 63;
  const int quad = l >> 4, qr = l & 15;
  const int node0 = blockIdx.x * 16;

  // A fragments: x rows node0..node0+15, all K=128 (4 ktiles)
  bf16x8 A[4];
  const float4* X4 = (const float4*)(x + (size_t)(node0 + qr) * EMB);
#pragma unroll
  for (int kt = 0; kt < 4; kt++) {
    float4 a0 = X4[kt * 8 + quad * 2];
    float4 a1 = X4[kt * 8 + quad * 2 + 1];
    A[kt][0] = (short)f2bf(a0.x); A[kt][1] = (short)f2bf(a0.y);
    A[kt][2] = (short)f2bf(a0.z); A[kt][3] = (short)f2bf(a0.w);
    A[kt][4] = (short)f2bf(a1.x); A[kt][5] = (short)f2bf(a1.y);
    A[kt][6] = (short)f2bf(a1.z); A[kt][7] = (short)f2bf(a1.w);
  }

  f32x4 acc[4];
  const uint4* B4 = (const uint4*)Bbuf;
#pragma unroll
  for (int nt = 0; nt < 4; nt++) {
    acc[nt] = (f32x4){0.f, 0.f, 0.f, 0.f};
    const int ntg = w * 4 + nt;
#pragma unroll
    for (int kt = 0; kt < 4; kt++) {
      uint4 br = B4[(kt * 16 + ntg) * 64 + l];
      bf16x8 B;
      B[0] = (short)(br.x & 0xFFFF); B[1] = (short)(br.x >> 16);
      B[2] = (short)(br.y & 0xFFFF); B[3] = (short)(br.y >> 16);
      B[4] = (short)(br.z & 0xFFFF); B[5] = (short)(br.z >> 16);
      B[6] = (short)(br.w & 0xFFFF); B[7] = (short)(br.w >> 16);
      acc[nt] = __builtin_amdgcn_mfma_f32_16x16x32_bf16(A[kt], B, acc[nt], 0, 0, 0);
    }
  }

  // epilogue: bf16 h1 stores + per-head att dots
  float ps_s[4][2] = {};  // [reg][head-local]
  float ps_d[4][2] = {};
#pragma unroll
  for (int nt = 0; nt < 4; nt++) {
    const int colg = w * 64 + nt * 16 + qr;
    const float as = asw[colg], ad = adw[colg];
    const int hh = nt >> 1;
#pragma unroll
    for (int reg = 0; reg < 4; reg++) {
      float v = acc[nt][reg];
      int row = node0 + quad * 4 + reg;
      h1b[(size_t)row * HID + colg] = f2bf(v);
      ps_s[reg][hh] += v * as;
      ps_d[reg][hh] += v * ad;
    }
  }
#pragma unroll
  for (int reg = 0; reg < 4; reg++) {
#pragma unroll
    for (int hh = 0; hh < 2; hh++) {
      float vs = ps_s[reg][hh], vd = ps_d[reg][hh];
      vs += __shfl_xor(vs, 8, 64); vs += __shfl_xor(vs, 4, 64);
      vs += __shfl_xor(vs, 2, 64); vs += __shfl_xor(vs, 1, 64);
      vd += __shfl_xor(vd, 8, 64); vd += __shfl_xor(vd, 4, 64);
      vd += __shfl_xor(vd, 2, 64); vd += __shfl_xor(vd, 1, 64);
      if (qr == 0) {
        int row = node0 + quad * 4 + reg;
        int head = 2 * w + hh;
        a_src[row * NH + head] = vs;
        a_dst[row * NH + head] = vd;
      }
    }
  }
}

// ---------- Layer-1 aggregation: half-wave edge-parallel ------------------
__global__ __launch_bounds__(256) void k_agg1(const int* __restrict__ rowp,
    const int* __restrict__ col, const float* __restrict__ a_src,
    const float* __restrict__ a_dst, const u16* __restrict__ h1b,
    const float* __restrict__ b1, float* __restrict__ x2) {
  int node = (blockIdx.x * 256 + threadIdx.x) >> 6;
  if (node >= NN) return;
  const int lane = threadIdx.x & 63;
  const int half = lane >> 5;
  const int hl = lane & 31;     // owns cols 8*hl .. 8*hl+7
  const int h = hl >> 2;        // head
  const float ad = a_dst[node * NH + h];
  float num[8] = {};
  float den = 0.f;
  const int beg = rowp[node], end = rowp[node + 1];
  int e = beg + half;
  int sn = (e < end) ? col[e] : 0;
  for (; e < end; e += 2) {
    int s = sn;
    if (e + 2 < end) sn = col[e + 2];
    float w = __expf(lrelu(a_src[s * NH + h] + ad));
    uint4 hv = ((const uint4*)(h1b + (size_t)s * HID))[hl];
    den += w;
    num[0] += w * bfl(hv.x); num[1] += w * bfh(hv.x);
    num[2] += w * bfl(hv.y); num[3] += w * bfh(hv.y);
    num[4] += w * bfl(hv.z); num[5] += w * bfh(hv.z);
    num[6] += w * bfl(hv.w); num[7] += w * bfh(hv.w);
  }
  den += __shfl_xor(den, 32, 64);
#pragma unroll
  for (int j = 0; j < 8; j++) num[j] += __shfl_xor(num[j], 32, 64);
  if (half == 0) {
    const float inv = 1.f / (den + 1e-16f);
    const float4 b0 = ((const float4*)(b1 + hl * 8))[0];
    const float4 b1v = ((const float4*)(b1 + hl * 8))[1];
    float4 o0, o1;
    o0.x = elu(num[0] * inv + b0.x);
    o0.y = elu(num[1] * inv + b0.y);
    o0.z = elu(num[2] * inv + b0.z);
    o0.w = elu(num[3] * inv + b0.w);
    o1.x = elu(num[4] * inv + b1v.x);
    o1.y = elu(num[5] * inv + b1v.y);
    o1.z = elu(num[6] * inv + b1v.z);
    o1.w = elu(num[7] * inv + b1v.w);
    float* po = x2 + (size_t)node * HID + hl * 8;
    ((float4*)po)[0] = o0;
    ((float4*)po)[1] = o1;
  }
}

// ---------- GEMM 2: h2 = x2 @ W2 [N,64] (bf16 out) + scalar att dots ------
__global__ __launch_bounds__(256) void k_gemm2(const float* __restrict__ x2,
    const float* __restrict__ W2, const float* __restrict__ asw,
    const float* __restrict__ adw, u16* __restrict__ h2b,
    float* __restrict__ a_src2, float* __restrict__ a_dst2) {
  __shared__ float xs[G2_ROWS][HIDP];
  const int tid = threadIdx.x;
  const int node0 = blockIdx.x * G2_ROWS;
  for (int i = tid; i < G2_ROWS * (HID / 4); i += 256) {
    int r = i >> 6, c4 = i & 63;
    float4 v = {0.f, 0.f, 0.f, 0.f};
    if (node0 + r < NN) v = ((const float4*)(x2 + (size_t)(node0 + r) * HID))[c4];
    *((float4*)&xs[r][c4 * 4]) = v;
  }
  __syncthreads();
  const int ct = tid & 15;
  const int rg = tid >> 4;
  float acc[2][4] = {};
  const float4* W4 = (const float4*)W2;
  for (int k = 0; k < HID; k += 4) {
    float4 w0 = W4[(k + 0) * 16 + ct];
    float4 w1 = W4[(k + 1) * 16 + ct];
    float4 w2 = W4[(k + 2) * 16 + ct];
    float4 w3 = W4[(k + 3) * 16 + ct];
#pragma unroll
    for (int r = 0; r < 2; r++) {
      float4 xv = *((const float4*)&xs[rg * 2 + r][k]);
      acc[r][0] += xv.x * w0.x + xv.y * w1.x + xv.z * w2.x + xv.w * w3.x;
      acc[r][1] += xv.x * w0.y + xv.y * w1.y + xv.z * w2.y + xv.w * w3.y;
      acc[r][2] += xv.x * w0.z + xv.y * w1.z + xv.z * w2.z + xv.w * w3.z;
      acc[r][3] += xv.x * w0.w + xv.y * w1.w + xv.z * w2.w + xv.w * w3.w;
    }
  }
  const float4 as4 = ((const float4*)asw)[ct];
  const float4 ad4 = ((const float4*)adw)[ct];
#pragma unroll
  for (int r = 0; r < 2; r++) {
    int n = node0 + rg * 2 + r;
    bool valid = n < NN;
    ushort4 hb;
    hb.x = f2bf(acc[r][0]); hb.y = f2bf(acc[r][1]);
    hb.z = f2bf(acc[r][2]); hb.w = f2bf(acc[r][3]);
    if (valid) ((ushort4*)(h2b + (size_t)n * RP))[ct] = hb;
    float vs = acc[r][0] * as4.x + acc[r][1] * as4.y + acc[r][2] * as4.z + acc[r][3] * as4.w;
    float vd = acc[r][0] * ad4.x + acc[r][1] * ad4.y + acc[r][2] * ad4.z + acc[r][3] * ad4.w;
    vs += __shfl_down(vs, 8, 16); vs += __shfl_down(vs, 4, 16);
    vs += __shfl_down(vs, 2, 16); vs += __shfl_down(vs, 1, 16);
    vd += __shfl_down(vd, 8, 16); vd += __shfl_down(vd, 4, 16);
    vd += __shfl_down(vd, 2, 16); vd += __shfl_down(vd, 1, 16);
    if (valid && ct == 0) { a_src2[n] = vs; a_dst2[n] = vd; }
  }
}

// ---------- Layer-2 aggregation: quarter-wave edge-parallel ---------------
__global__ __launch_bounds__(256) void k_agg2(const int* __restrict__ rowp,
    const int* __restrict__ col, const float* __restrict__ a_src2,
    const float* __restrict__ a_dst2, const u16* __restrict__ h2b,
    const float* __restrict__ b2, float* __restrict__ out) {
  int node = (blockIdx.x * 256 + threadIdx.x) >> 6;
  if (node >= NN) return;
  const int lane = threadIdx.x & 63;
  const int q = lane >> 4;
  const int ql = lane & 15;     // owns cols 4*ql .. 4*ql+3
  const float ad = a_dst2[node];
  float num[4] = {};
  float den = 0.f;
  const int beg = rowp[node], end = rowp[node + 1];
  int e = beg + q;
  int sn = (e < end) ? col[e] : 0;
  for (; e < end; e += 4) {
    int s = sn;
    if (e + 4 < end) sn = col[e + 4];
    float w = __expf(lrelu(a_src2[s] + ad));
    uint2 hv = ((const uint2*)(h2b + (size_t)s * RP))[ql];
    den += w;
    num[0] += w * bfl(hv.x); num[1] += w * bfh(hv.x);
    num[2] += w * bfl(hv.y); num[3] += w * bfh(hv.y);
  }
  den += __shfl_xor(den, 16, 64);
  den += __shfl_xor(den, 32, 64);
#pragma unroll
  for (int j = 0; j < 4; j++) {
    num[j] += __shfl_xor(num[j], 16, 64);
    num[j] += __shfl_xor(num[j], 32, 64);
  }
  if (q == 0) {
    const float inv = 1.f / (den + 1e-16f);
    const float4 b = ((const float4*)(b2 + ql * 4))[0];
    float4 o;
    o.x = num[0] * inv + b.x;
    o.y = num[1] * inv + b.y;
    o.z = num[2] * inv + b.z;
    o.w = num[3] * inv + b.w;
    ((float4*)(out + (size_t)node * RP + ql * 4))[0] = o;
  }
}

extern "C" void kernel_launch(void* const* d_in, const int* in_sizes, int n_in,
                              void* d_out, int out_size, void* d_ws, size_t ws_size,
                              hipStream_t stream) {
  const float* x   = (const float*)d_in[0];
  const float* W1  = (const float*)d_in[1];
  const float* a1s = (const float*)d_in[2];
  const float* a1d = (const float*)d_in[3];
  const float* b1  = (const float*)d_in[4];
  const float* W2  = (const float*)d_in[5];
  const float* a2s = (const float*)d_in[6];
  const float* a2d = (const float*)d_in[7];
  const float* b2  = (const float*)d_in[8];
  const int*   es  = (const int*)d_in[9];
  const int*   ed  = es + EE;
  float* out = (float*)d_out;

  // workspace layout
  u16*   h1b   = (u16*)d_ws;                        // N*256 bf16 (reused as h2b)
  float* x2    = (float*)(h1b + (size_t)NN * HID);  // N*256 f32
  float* asrc1 = x2 + (size_t)NN * HID;             // N*8
  float* adst1 = asrc1 + (size_t)NN * NH;           // N*8
  int*   deg   = (int*)(adst1 + (size_t)NN * NH);   // N
  int*   rowp  = deg + NN;                          // N+1
  int*   cursor = rowp + NN + 1;                    // N
  int*   bsum  = cursor + NN;                       // NBLK
  int*   col   = bsum + NBLK;                       // ET
  u16*   Bbuf  = (u16*)(col + ET);                  // 128*256 bf16 frag-major
  u16*   h2b   = h1b;
  float* asrc2 = asrc1;
  float* adst2 = adst1;

  hipMemsetAsync(deg, 0, (size_t)NN * sizeof(int), stream);

  // degree count + W1 bf16 frag-prep (independent, fused)
  k_pre<<<DEG_BLOCKS + BP_BLOCKS, 256, 0, stream>>>(ed, deg, W1, Bbuf);
  k_scan1<<<NBLK, 256, 0, stream>>>(deg, rowp, bsum);
  k_scan2<<<1, 256, 0, stream>>>(bsum);
  k_scan3<<<NBLK, 256, 0, stream>>>(rowp, bsum, cursor);

  // MFMA GEMM1 fused with CSR fill
  k_gemm1m_fill<<<G1M_BLOCKS + FILL_BLOCKS, 256, 0, stream>>>(
      x, Bbuf, a1s, a1d, h1b, asrc1, adst1, es, ed, cursor, col);

  k_agg1<<<(NN * 64 + 255) / 256, 256, 0, stream>>>(rowp, col, asrc1, adst1, h1b, b1, x2);
  k_gemm2<<<(NN + G2_ROWS - 1) / G2_ROWS, 256, 0, stream>>>(x2, W2, a2s, a2d, h2b, asrc2, adst2);
  k_agg2<<<(NN * 64 + 255) / 256, 256, 0, stream>>>(rowp, col, asrc2, adst2, h2b, b2, out);
}

// Round 7
// 227.705 us; speedup vs baseline: 10.7755x; 1.3385x over previous
//
#include <hip/hip_runtime.h>

#define NN 50000      // nodes
#define EE 500000     // raw edges
#define ET 550000     // edges + self loops
#define EMB 128
#define HID 256
#define NH 8
#define RP 64
#define NBLK ((NN + 255) / 256)   // 196 scan blocks
#define G1M_BLOCKS (NN / 16)                       // 3125 MFMA m-tiles
#define EDGE_BLOCKS ((ET + 255) / 256)             // 2149
#define W1P_BLOCKS 16                              // W1 frag-prep blocks
#define W2P_BLOCKS 8                               // W2 frag-prep blocks
#define G2M_BLOCKS ((NN + 63) / 64)                // 782

typedef unsigned short u16;
typedef __attribute__((ext_vector_type(8))) short bf16x8;
typedef __attribute__((ext_vector_type(4))) float f32x4;

__device__ __forceinline__ float lrelu(float v) { return v > 0.f ? v : 0.2f * v; }
__device__ __forceinline__ float elu(float v) { return v > 0.f ? v : __expf(v) - 1.f; }
__device__ __forceinline__ u16 f2bf(float f) {
  unsigned int u = __float_as_uint(f);
  u += 0x7FFFu + ((u >> 16) & 1u);
  return (u16)(u >> 16);
}
__device__ __forceinline__ float bfl(unsigned int u) { return __uint_as_float(u << 16); }
__device__ __forceinline__ float bfh(unsigned int u) { return __uint_as_float(u & 0xFFFF0000u); }

// ---------- k_pre: zero deg | W1 frag prep | W2 frag prep -----------------
__global__ __launch_bounds__(256) void k_pre(int* __restrict__ deg,
    const float* __restrict__ W1, u16* __restrict__ Bbuf,
    const float* __restrict__ W2, u16* __restrict__ Bbuf2) {
  const int tid = threadIdx.x;
  const int b = blockIdx.x;
  if (b < NBLK) {                     // zero deg
    int idx = b * 256 + tid;
    if (idx < NN) deg[idx] = 0;
    return;
  }
  const int l = tid & 63;
  const int quad = l >> 4, qr = l & 15;
  if (b < NBLK + W1P_BLOCKS) {        // W1 -> bf16 B-frags (16 blocks x 4 waves)
    const int tile = (b - NBLK) * 4 + (tid >> 6);  // kt*16+nt, kt<4, nt<16
    const int kt = tile >> 4, nt = tile & 15;
    const float* src = W1 + (size_t)(kt * 32 + quad * 8) * HID + nt * 16 + qr;
    unsigned int p[4];
#pragma unroll
    for (int jp = 0; jp < 4; jp++) {
      u16 lo = f2bf(src[(2 * jp + 0) * HID]);
      u16 hi = f2bf(src[(2 * jp + 1) * HID]);
      p[jp] = (unsigned int)lo | ((unsigned int)hi << 16);
    }
    ((uint4*)Bbuf)[tile * 64 + l] = (uint4){p[0], p[1], p[2], p[3]};
    return;
  }
  // W2 -> bf16 B-frags (8 blocks x 4 waves = 32 tiles: kt<8, nt<4)
  const int tile = (b - NBLK - W1P_BLOCKS) * 4 + (tid >> 6);  // kt*4+nt
  const int kt = tile >> 2, nt = tile & 3;
  const float* src = W2 + (size_t)(kt * 32 + quad * 8) * RP + nt * 16 + qr;
  unsigned int p[4];
#pragma unroll
  for (int jp = 0; jp < 4; jp++) {
    u16 lo = f2bf(src[(2 * jp + 0) * RP]);
    u16 hi = f2bf(src[(2 * jp + 1) * RP]);
    p[jp] = (unsigned int)lo | ((unsigned int)hi << 16);
  }
  ((uint4*)Bbuf2)[tile * 64 + l] = (uint4){p[0], p[1], p[2], p[3]};
}

// ---------- GEMM1 MFMA + fused deg/rank atomic pass -----------------------
__global__ __launch_bounds__(256) void k_g1rank(const float* __restrict__ x,
    const u16* __restrict__ Bbuf, const float* __restrict__ asw,
    const float* __restrict__ adw, u16* __restrict__ h1b,
    float* __restrict__ a_src, float* __restrict__ a_dst,
    const int* __restrict__ es, const int* __restrict__ ed,
    int* __restrict__ deg, int* __restrict__ rank) {
  const int tid = threadIdx.x;
  if (blockIdx.x >= G1M_BLOCKS) {
    // ---- deg count + per-edge rank (the single device-atomic pass) ----
    int i = (blockIdx.x - G1M_BLOCKS) * 256 + tid;
    if (i < ET) {
      int d = (i < EE) ? ed[i] : i - EE;
      rank[i] = atomicAdd(&deg[d], 1);
    }
    return;
  }
  const int w = tid >> 6, l = tid & 63;
  const int quad = l >> 4, qr = l & 15;
  const int node0 = blockIdx.x * 16;

  bf16x8 A[4];
  const float4* X4 = (const float4*)(x + (size_t)(node0 + qr) * EMB);
#pragma unroll
  for (int kt = 0; kt < 4; kt++) {
    float4 a0 = X4[kt * 8 + quad * 2];
    float4 a1 = X4[kt * 8 + quad * 2 + 1];
    A[kt][0] = (short)f2bf(a0.x); A[kt][1] = (short)f2bf(a0.y);
    A[kt][2] = (short)f2bf(a0.z); A[kt][3] = (short)f2bf(a0.w);
    A[kt][4] = (short)f2bf(a1.x); A[kt][5] = (short)f2bf(a1.y);
    A[kt][6] = (short)f2bf(a1.z); A[kt][7] = (short)f2bf(a1.w);
  }

  f32x4 acc[4];
  const bf16x8* Bf = (const bf16x8*)Bbuf;
#pragma unroll
  for (int nt = 0; nt < 4; nt++) {
    acc[nt] = (f32x4){0.f, 0.f, 0.f, 0.f};
    const int ntg = w * 4 + nt;
#pragma unroll
    for (int kt = 0; kt < 4; kt++) {
      bf16x8 B = Bf[(kt * 16 + ntg) * 64 + l];
      acc[nt] = __builtin_amdgcn_mfma_f32_16x16x32_bf16(A[kt], B, acc[nt], 0, 0, 0);
    }
  }

  float ps_s[4][2] = {};
  float ps_d[4][2] = {};
#pragma unroll
  for (int nt = 0; nt < 4; nt++) {
    const int colg = w * 64 + nt * 16 + qr;
    const float as = asw[colg], ad = adw[colg];
    const int hh = nt >> 1;
#pragma unroll
    for (int reg = 0; reg < 4; reg++) {
      float v = acc[nt][reg];
      int row = node0 + quad * 4 + reg;
      h1b[(size_t)row * HID + colg] = f2bf(v);
      ps_s[reg][hh] += v * as;
      ps_d[reg][hh] += v * ad;
    }
  }
#pragma unroll
  for (int reg = 0; reg < 4; reg++) {
#pragma unroll
    for (int hh = 0; hh < 2; hh++) {
      float vs = ps_s[reg][hh], vd = ps_d[reg][hh];
      vs += __shfl_xor(vs, 8, 64); vs += __shfl_xor(vs, 4, 64);
      vs += __shfl_xor(vs, 2, 64); vs += __shfl_xor(vs, 1, 64);
      vd += __shfl_xor(vd, 8, 64); vd += __shfl_xor(vd, 4, 64);
      vd += __shfl_xor(vd, 2, 64); vd += __shfl_xor(vd, 1, 64);
      if (qr == 0) {
        int row = node0 + quad * 4 + reg;
        int head = 2 * w + hh;
        a_src[row * NH + head] = vs;
        a_dst[row * NH + head] = vd;
      }
    }
  }
}

// ---------------- scans ---------------------------------------------------
__global__ __launch_bounds__(256) void k_scan1(const int* __restrict__ deg,
    int* __restrict__ rowp, int* __restrict__ bsum) {
  __shared__ int s[256];
  const int t = threadIdx.x;
  const int idx = blockIdx.x * 256 + t;
  const int v = (idx < NN) ? deg[idx] : 0;
  s[t] = v;
  __syncthreads();
  for (int off = 1; off < 256; off <<= 1) {
    int y = (t >= off) ? s[t - off] : 0;
    __syncthreads();
    s[t] += y;
    __syncthreads();
  }
  if (idx < NN) rowp[idx] = s[t] - v;
  if (t == 255) bsum[blockIdx.x] = s[255];
}

__global__ __launch_bounds__(256) void k_scan2(int* __restrict__ bsum) {
  __shared__ int s[256];
  const int t = threadIdx.x;
  const int v = (t < NBLK) ? bsum[t] : 0;
  s[t] = v;
  __syncthreads();
  for (int off = 1; off < 256; off <<= 1) {
    int y = (t >= off) ? s[t - off] : 0;
    __syncthreads();
    s[t] += y;
    __syncthreads();
  }
  if (t < NBLK) bsum[t] = s[t] - v;
}

__global__ __launch_bounds__(256) void k_scan3(int* __restrict__ rowp,
    const int* __restrict__ bsum) {
  const int idx = blockIdx.x * 256 + threadIdx.x;
  if (idx < NN) rowp[idx] += bsum[blockIdx.x];
  if (idx == 0) rowp[NN] = ET;
}

// ---------- atomic-free CSR scatter ---------------------------------------
__global__ __launch_bounds__(256) void k_scatter(const int* __restrict__ es,
    const int* __restrict__ ed, const int* __restrict__ rank,
    const int* __restrict__ rowp, int* __restrict__ col) {
  int i = blockIdx.x * 256 + threadIdx.x;
  if (i >= ET) return;
  int s, d;
  if (i < EE) { s = es[i]; d = ed[i]; } else { s = d = i - EE; }
  col[rowp[d] + rank[i]] = s;
}

// ---------- Layer-1 aggregation: half-wave edge-parallel, bf16 x2 out -----
__global__ __launch_bounds__(256) void k_agg1(const int* __restrict__ rowp,
    const int* __restrict__ col, const float* __restrict__ a_src,
    const float* __restrict__ a_dst, const u16* __restrict__ h1b,
    const float* __restrict__ b1, u16* __restrict__ x2b) {
  int node = (blockIdx.x * 256 + threadIdx.x) >> 6;
  if (node >= NN) return;
  const int lane = threadIdx.x & 63;
  const int half = lane >> 5;
  const int hl = lane & 31;     // owns cols 8*hl .. 8*hl+7
  const int h = hl >> 2;        // head
  const float ad = a_dst[node * NH + h];
  float num[8] = {};
  float den = 0.f;
  const int beg = rowp[node], end = rowp[node + 1];
  int e = beg + half;
  int sn = (e < end) ? col[e] : 0;
  for (; e < end; e += 2) {
    int s = sn;
    if (e + 2 < end) sn = col[e + 2];
    float w = __expf(lrelu(a_src[s * NH + h] + ad));
    uint4 hv = ((const uint4*)(h1b + (size_t)s * HID))[hl];
    den += w;
    num[0] += w * bfl(hv.x); num[1] += w * bfh(hv.x);
    num[2] += w * bfl(hv.y); num[3] += w * bfh(hv.y);
    num[4] += w * bfl(hv.z); num[5] += w * bfh(hv.z);
    num[6] += w * bfl(hv.w); num[7] += w * bfh(hv.w);
  }
  den += __shfl_xor(den, 32, 64);
#pragma unroll
  for (int j = 0; j < 8; j++) num[j] += __shfl_xor(num[j], 32, 64);
  if (half == 0) {
    const float inv = 1.f / (den + 1e-16f);
    const float4 b0 = ((const float4*)(b1 + hl * 8))[0];
    const float4 b1v = ((const float4*)(b1 + hl * 8))[1];
    float o[8];
    o[0] = elu(num[0] * inv + b0.x);
    o[1] = elu(num[1] * inv + b0.y);
    o[2] = elu(num[2] * inv + b0.z);
    o[3] = elu(num[3] * inv + b0.w);
    o[4] = elu(num[4] * inv + b1v.x);
    o[5] = elu(num[5] * inv + b1v.y);
    o[6] = elu(num[6] * inv + b1v.z);
    o[7] = elu(num[7] * inv + b1v.w);
    unsigned int dw[4];
#pragma unroll
    for (int jp = 0; jp < 4; jp++)
      dw[jp] = (unsigned int)f2bf(o[2 * jp]) | ((unsigned int)f2bf(o[2 * jp + 1]) << 16);
    ((uint4*)(x2b + (size_t)node * HID))[hl] = (uint4){dw[0], dw[1], dw[2], dw[3]};
  }
}

// ---------- GEMM 2 via MFMA: h2 = x2b @ W2 (bf16 out) + att dots ----------
// 64 nodes/block; wave w = rows [node0+16w, +16), all 64 cols, K=256
__global__ __launch_bounds__(256) void k_gemm2m(const u16* __restrict__ x2b,
    const u16* __restrict__ Bbuf2, const float* __restrict__ asw,
    const float* __restrict__ adw, u16* __restrict__ h2b,
    float* __restrict__ a_src2, float* __restrict__ a_dst2) {
  const int tid = threadIdx.x;
  const int w = tid >> 6, l = tid & 63;
  const int quad = l >> 4, qr = l & 15;
  const int row0 = blockIdx.x * 64 + w * 16;
  const int rowA = row0 + qr;
  const int rowA_ld = rowA < NN ? rowA : NN - 1;

  bf16x8 A[8];
  const bf16x8* Xa = (const bf16x8*)(x2b + (size_t)rowA_ld * HID);
#pragma unroll
  for (int kt = 0; kt < 8; kt++) A[kt] = Xa[kt * 4 + quad];

  f32x4 acc[4];
  const bf16x8* Bf = (const bf16x8*)Bbuf2;
#pragma unroll
  for (int nt = 0; nt < 4; nt++) {
    acc[nt] = (f32x4){0.f, 0.f, 0.f, 0.f};
#pragma unroll
    for (int kt = 0; kt < 8; kt++) {
      bf16x8 B = Bf[(kt * 4 + nt) * 64 + l];
      acc[nt] = __builtin_amdgcn_mfma_f32_16x16x32_bf16(A[kt], B, acc[nt], 0, 0, 0);
    }
  }

  float ps_s[4] = {}, ps_d[4] = {};
#pragma unroll
  for (int nt = 0; nt < 4; nt++) {
    const int colg = nt * 16 + qr;
    const float as = asw[colg], ad = adw[colg];
#pragma unroll
    for (int reg = 0; reg < 4; reg++) {
      float v = acc[nt][reg];
      int row = row0 + quad * 4 + reg;
      if (row < NN) h2b[(size_t)row * RP + colg] = f2bf(v);
      ps_s[reg] += v * as;
      ps_d[reg] += v * ad;
    }
  }
#pragma unroll
  for (int reg = 0; reg < 4; reg++) {
    float vs = ps_s[reg], vd = ps_d[reg];
    vs += __shfl_xor(vs, 8, 64); vs += __shfl_xor(vs, 4, 64);
    vs += __shfl_xor(vs, 2, 64); vs += __shfl_xor(vs, 1, 64);
    vd += __shfl_xor(vd, 8, 64); vd += __shfl_xor(vd, 4, 64);
    vd += __shfl_xor(vd, 2, 64); vd += __shfl_xor(vd, 1, 64);
    int row = row0 + quad * 4 + reg;
    if (qr == 0 && row < NN) { a_src2[row] = vs; a_dst2[row] = vd; }
  }
}

// ---------- Layer-2 aggregation: quarter-wave edge-parallel ---------------
__global__ __launch_bounds__(256) void k_agg2(const int* __restrict__ rowp,
    const int* __restrict__ col, const float* __restrict__ a_src2,
    const float* __restrict__ a_dst2, const u16* __restrict__ h2b,
    const float* __restrict__ b2, float* __restrict__ out) {
  int node = (blockIdx.x * 256 + threadIdx.x) >> 6;
  if (node >= NN) return;
  const int lane = threadIdx.x & 63;
  const int q = lane >> 4;
  const int ql = lane & 15;     // owns cols 4*ql .. 4*ql+3
  const float ad = a_dst2[node];
  float num[4] = {};
  float den = 0.f;
  const int beg = rowp[node], end = rowp[node + 1];
  int e = beg + q;
  int sn = (e < end) ? col[e] : 0;
  for (; e < end; e += 4) {
    int s = sn;
    if (e + 4 < end) sn = col[e + 4];
    float w = __expf(lrelu(a_src2[s] + ad));
    uint2 hv = ((const uint2*)(h2b + (size_t)s * RP))[ql];
    den += w;
    num[0] += w * bfl(hv.x); num[1] += w * bfh(hv.x);
    num[2] += w * bfl(hv.y); num[3] += w * bfh(hv.y);
  }
  den += __shfl_xor(den, 16, 64);
  den += __shfl_xor(den, 32, 64);
#pragma unroll
  for (int j = 0; j < 4; j++) {
    num[j] += __shfl_xor(num[j], 16, 64);
    num[j] += __shfl_xor(num[j], 32, 64);
  }
  if (q == 0) {
    const float inv = 1.f / (den + 1e-16f);
    const float4 b = ((const float4*)(b2 + ql * 4))[0];
    float4 o;
    o.x = num[0] * inv + b.x;
    o.y = num[1] * inv + b.y;
    o.z = num[2] * inv + b.z;
    o.w = num[3] * inv + b.w;
    ((float4*)(out + (size_t)node * RP + ql * 4))[0] = o;
  }
}

extern "C" void kernel_launch(void* const* d_in, const int* in_sizes, int n_in,
                              void* d_out, int out_size, void* d_ws, size_t ws_size,
                              hipStream_t stream) {
  const float* x   = (const float*)d_in[0];
  const float* W1  = (const float*)d_in[1];
  const float* a1s = (const float*)d_in[2];
  const float* a1d = (const float*)d_in[3];
  const float* b1  = (const float*)d_in[4];
  const float* W2  = (const float*)d_in[5];
  const float* a2s = (const float*)d_in[6];
  const float* a2d = (const float*)d_in[7];
  const float* b2  = (const float*)d_in[8];
  const int*   es  = (const int*)d_in[9];
  const int*   ed  = es + EE;
  float* out = (float*)d_out;

  // workspace layout
  u16*   h1b   = (u16*)d_ws;                        // N*256 bf16 (reused as h2b)
  u16*   x2b   = h1b + (size_t)NN * HID;            // N*256 bf16
  float* asrc1 = (float*)(x2b + (size_t)NN * HID);  // N*8
  float* adst1 = asrc1 + (size_t)NN * NH;           // N*8
  int*   deg   = (int*)(adst1 + (size_t)NN * NH);   // N
  int*   rowp  = deg + NN;                          // N+1
  int*   rank  = rowp + NN + 1;                     // ET
  int*   bsum  = rank + ET;                         // NBLK
  int*   col   = bsum + NBLK;                       // ET
  u16*   Bbuf  = (u16*)(col + ET);                  // 128*256 bf16 frag-major
  u16*   Bbuf2 = Bbuf + (size_t)EMB * HID;          // 256*64 bf16 frag-major
  u16*   h2b   = h1b;
  float* asrc2 = asrc1;
  float* adst2 = adst1;

  // opener: zero deg | W1 prep | W2 prep
  k_pre<<<NBLK + W1P_BLOCKS + W2P_BLOCKS, 256, 0, stream>>>(deg, W1, Bbuf, W2, Bbuf2);

  // MFMA GEMM1 fused with the single atomic pass (deg + rank)
  k_g1rank<<<G1M_BLOCKS + EDGE_BLOCKS, 256, 0, stream>>>(
      x, Bbuf, a1s, a1d, h1b, asrc1, adst1, es, ed, deg, rank);

  k_scan1<<<NBLK, 256, 0, stream>>>(deg, rowp, bsum);
  k_scan2<<<1, 256, 0, stream>>>(bsum);
  k_scan3<<<NBLK, 256, 0, stream>>>(rowp, bsum);
  k_scatter<<<EDGE_BLOCKS, 256, 0, stream>>>(es, ed, rank, rowp, col);

  k_agg1<<<(NN * 64 + 255) / 256, 256, 0, stream>>>(rowp, col, asrc1, adst1, h1b, b1, x2b);
  k_gemm2m<<<G2M_BLOCKS, 256, 0, stream>>>(x2b, Bbuf2, a2s, a2d, h2b, asrc2, adst2);
  k_agg2<<<(NN * 64 + 255) / 256, 256, 0, stream>>>(rowp, col, asrc2, adst2, h2b, b2, out);
}